// Round 10
// baseline (1528.411 us; speedup 1.0000x reference)
//
#include <hip/hip_runtime.h>
#include <math.h>

#define KNN 75
#define NL 8
#define NB 1024
#define NT 50000
#define NT_PAD 50048  // NTB*TT rows allocated for bf16 banks (pad rows masked)
#define NCALI 10000
#define KC 32
#define QT 64
#define TT 128
#define NTB 391       // ceil(NT/TT)
#define SLOTS 16      // per (q, t-block) slab: [count, up to 15 hit keys] = 64B
#define CAP 6144      // candidate buffer per query
#define NSUB 2048     // sampled train points for threshold
#define SSTRIDE 24
#define SOFF 11       // 11 + 24*2047 = 49139 < 50000
#define RSEL 32       // sample rank -> expected |{k < T}| ~ 780, lambda/slab ~ 2

typedef __attribute__((ext_vector_type(8))) short bf16x8;
typedef __attribute__((ext_vector_type(4))) float f32x4;

__device__ __forceinline__ int swz(int c){ return c + ((c>>5)<<2); }

__device__ __forceinline__ unsigned short f2bf_rn(float x){
  unsigned u = __float_as_uint(x);
  unsigned r = (u + 0x7FFFu + ((u>>16)&1u)) >> 16;
  return (unsigned short)r;
}
__device__ __forceinline__ float bf2f(unsigned short h){
  return __uint_as_float(((unsigned)h)<<16);
}
__device__ __forceinline__ bf16x8 ld8(const unsigned short* p){
  return *(const bf16x8*)p;
}
// async global->LDS, 16B per lane; LDS dest = wave-uniform base + lane*16
__device__ __forceinline__ void gl_lds16(const unsigned short* g, unsigned short* l){
  __builtin_amdgcn_global_load_lds(
      (const __attribute__((address_space(1))) void*)g,
      (__attribute__((address_space(3))) void*)l, 16, 0, 0);
}

// ---------------- pad copy (zero-fill pad cols every call: ws is poisoned) ----
__global__ void pad_copy_k(const float* __restrict__ in, float* __restrict__ out,
                           int M, int Din, int Dout){
  int idx = blockIdx.x*256 + threadIdx.x;
  if (idx >= M*Dout) return;
  int r = idx / Dout, c = idx - r*Dout;
  out[idx] = (c < Din) ? in[r*Din + c] : 0.f;
}

// ---------------- MLP GEMM: Out = relu(A@W+b), fused bf16-split + row norms ---
// Out[M][128] fp32; H/L[M][128] bf16 hi/lo; nrm[M] row squared-norm.
__global__ __launch_bounds__(256) void mlp_gemm_k(
    const float* __restrict__ A, int lda, int kchunks,
    const float* __restrict__ W, int kreal,
    const float* __restrict__ bias,
    float* __restrict__ Out,
    unsigned short* __restrict__ H, unsigned short* __restrict__ L,
    float* __restrict__ nrm, int M)
{
  __shared__ float As[KC][132];
  __shared__ float Bs[KC][148];
  __shared__ float nrm_s[128][17];
  int tid = threadIdx.x;
  int r0 = (tid>>4)*8, c0 = (tid&15)*8;
  int rowBase = blockIdx.x*128;
  float acc[8][8];
  #pragma unroll
  for (int i=0;i<8;i++)
    #pragma unroll
    for (int j=0;j<8;j++) acc[i][j]=0.f;

  for (int kc=0;kc<kchunks;kc++){
    { int rr = tid>>3, k4=(tid&7)*4;
      #pragma unroll
      for (int i=0;i<4;i++){
        int row = rr + i*32, gr = rowBase + row;
        float4 v = make_float4(0.f,0.f,0.f,0.f);
        if (gr < M) v = *(const float4*)&A[(size_t)gr*lda + kc*KC + k4];
        As[k4+0][row]=v.x; As[k4+1][row]=v.y; As[k4+2][row]=v.z; As[k4+3][row]=v.w;
      }
    }
    { int kk=tid>>5, c4=(tid&31)*4;
      #pragma unroll
      for (int i=0;i<4;i++){
        int k = kk + i*8, gk = kc*KC + k;
        float4 v = make_float4(0.f,0.f,0.f,0.f);
        if (gk < kreal) v = *(const float4*)&W[(size_t)gk*128 + c4];
        *(float4*)&Bs[k][swz(c4)] = v;
      }
    }
    __syncthreads();
    #pragma unroll 4
    for (int k=0;k<KC;k++){
      float4 a0 = *(const float4*)&As[k][r0];
      float4 a1 = *(const float4*)&As[k][r0+4];
      float4 b0 = *(const float4*)&Bs[k][swz(c0)];
      float4 b1 = *(const float4*)&Bs[k][swz(c0+4)];
      float av[8] = {a0.x,a0.y,a0.z,a0.w,a1.x,a1.y,a1.z,a1.w};
      float bv[8] = {b0.x,b0.y,b0.z,b0.w,b1.x,b1.y,b1.z,b1.w};
      #pragma unroll
      for (int i=0;i<8;i++)
        #pragma unroll
        for (int j=0;j<8;j++) acc[i][j] += av[i]*bv[j];
    }
    __syncthreads();
  }
  float bb[8];
  #pragma unroll
  for (int j=0;j<8;j++) bb[j]=bias[c0+j];
  #pragma unroll
  for (int i=0;i<8;i++){
    int gr = rowBase + r0 + i;
    float o[8]; float part=0.f;
    #pragma unroll
    for (int j=0;j<8;j++){
      float v=acc[i][j]+bb[j]; v = v>0.f?v:0.f; o[j]=v; part += v*v;
    }
    nrm_s[r0+i][tid&15] = part;
    if (gr < M){
      *(float4*)&Out[(size_t)gr*128 + c0]   = make_float4(o[0],o[1],o[2],o[3]);
      *(float4*)&Out[(size_t)gr*128 + c0+4] = make_float4(o[4],o[5],o[6],o[7]);
      unsigned short hh[8], ll[8];
      #pragma unroll
      for (int j=0;j<8;j++){
        unsigned short h = f2bf_rn(o[j]);
        hh[j]=h; ll[j]=f2bf_rn(o[j]-bf2f(h));
      }
      *(uint4*)&H[(size_t)gr*128 + c0] = *(uint4*)hh;
      *(uint4*)&L[(size_t)gr*128 + c0] = *(uint4*)ll;
    }
  }
  __syncthreads();
  if (tid < 128){
    int gr = rowBase + tid;
    if (gr < M){
      float s=0.f;
      #pragma unroll
      for (int cg=0;cg<16;cg++) s += nrm_s[tid][cg];
      nrm[gr]=s;
    }
  }
}

// ---------------- last layer: logits[M][8] into stride-32 rows ----------------
__global__ void mlp8_k(const float* __restrict__ A, const float* __restrict__ W4,
                       const float* __restrict__ b4, float* __restrict__ Out, int M){
  __shared__ float Ws[128*8];
  int tid = threadIdx.x;
  for (int i=tid;i<1024;i+=256) Ws[i]=W4[i];
  __syncthreads();
  int r = blockIdx.x*32 + (tid>>3), c = tid&7;
  if (r >= M) return;
  const float* a = &A[(size_t)r*128];
  float acc = b4[c];
  #pragma unroll 16
  for (int k=0;k<128;k++) acc += a[k]*Ws[k*8+c];
  Out[(size_t)r*32 + c] = acc;
}

// ---------------- softmax over 8 logits, zero cols 8..31 ----------------------
__global__ void softmax_k(float* __restrict__ X, int M){
  int r = blockIdx.x*256 + threadIdx.x;
  if (r >= M) return;
  float* p = &X[(size_t)r*32];
  float v[8], m=-1e30f;
  #pragma unroll
  for (int j=0;j<8;j++){ v[j]=p[j]; m = v[j]>m ? v[j] : m; }
  float s=0.f;
  #pragma unroll
  for (int j=0;j<8;j++){ v[j]=__expf(v[j]-m); s+=v[j]; }
  float inv=1.f/s;
  #pragma unroll
  for (int j=0;j<8;j++) p[j]=v[j]*inv;
  #pragma unroll
  for (int j=8;j<32;j++) p[j]=0.f;
}

// ---------------- fp32 -> (hi,lo) bf16 split + row squared-norms --------------
__global__ void conv_norm_k(const float* __restrict__ X,
                            unsigned short* __restrict__ H,
                            unsigned short* __restrict__ L,
                            float* __restrict__ nrm, int M, int dp){
  int w = threadIdx.x>>6, lane = threadIdx.x&63;
  int row = blockIdx.x*4 + w;
  if (row >= M) return;
  const float* src = &X[(size_t)row*dp];
  unsigned short* dh = &H[(size_t)row*dp];
  unsigned short* dl = &L[(size_t)row*dp];
  float s=0.f;
  for (int c=lane;c<dp;c+=64){
    float v = src[c];
    s += v*v;
    unsigned short h = f2bf_rn(v);
    float rem = v - bf2f(h);
    dh[c] = h;
    dl[c] = f2bf_rn(rem);
  }
  #pragma unroll
  for (int off=32;off>0;off>>=1) s += __shfl_down(s, off, 64);
  if (lane==0) nrm[row]=s;
}

// ---------------- gather sampled subset bank + its norms ----------------------
__global__ void sub_gather_k(const float* __restrict__ Bank, const float* __restrict__ tnb,
                             float* __restrict__ Tsub, float* __restrict__ tnsub, int dp){
  int idx = blockIdx.x*256 + threadIdx.x;
  int total = NSUB*dp;
  if (idx < total){
    int s = idx/dp, c = idx - s*dp;
    Tsub[idx] = Bank[(size_t)(s*SSTRIDE+SOFF)*dp + c];
  } else if (idx < total + NSUB){
    int s = idx - total;
    tnsub[s] = tnb[s*SSTRIDE+SOFF];
  }
}

// ---------------- subset distance GEMM (fp32) -> packed keys ------------------
__global__ __launch_bounds__(256) void dist_key_k(
    const float* __restrict__ Qm, const float* __restrict__ Tm,
    const float* __restrict__ qn, const float* __restrict__ tn,
    const int* __restrict__ labels, unsigned* __restrict__ keys, int dp, int nt)
{
  __shared__ float qs[KC][68];
  __shared__ float ts[KC][148];
  int tid = threadIdx.x;
  int qbase = blockIdx.x*QT;
  int n0 = blockIdx.y*TT;
  int kchunks = dp >> 5;
  int r0 = (tid>>4)*4, c0=(tid&15)*8;
  float acc[4][8];
  #pragma unroll
  for (int i=0;i<4;i++)
    #pragma unroll
    for (int j=0;j<8;j++) acc[i][j]=0.f;

  for (int kc=0;kc<kchunks;kc++){
    { int qq0=tid>>3, k4=(tid&7)*4;
      #pragma unroll
      for (int i=0;i<2;i++){
        int qq=qq0+i*32;
        float4 v = *(const float4*)&Qm[(size_t)(qbase+qq)*dp + kc*KC + k4];
        qs[k4+0][qq]=v.x; qs[k4+1][qq]=v.y; qs[k4+2][qq]=v.z; qs[k4+3][qq]=v.w;
      }
    }
    { int tt0=tid>>3, k4=(tid&7)*4;
      #pragma unroll
      for (int i=0;i<4;i++){
        int ttI=tt0+i*32, g=n0+ttI;
        float4 v = make_float4(0.f,0.f,0.f,0.f);
        if (g < nt) v = *(const float4*)&Tm[(size_t)g*dp + kc*KC + k4];
        int o=swz(ttI);
        ts[k4+0][o]=v.x; ts[k4+1][o]=v.y; ts[k4+2][o]=v.z; ts[k4+3][o]=v.w;
      }
    }
    __syncthreads();
    #pragma unroll 8
    for (int k=0;k<KC;k++){
      float4 a  = *(const float4*)&qs[k][r0];
      float4 b0 = *(const float4*)&ts[k][swz(c0)];
      float4 b1 = *(const float4*)&ts[k][swz(c0+4)];
      float av[4]={a.x,a.y,a.z,a.w};
      float bv[8]={b0.x,b0.y,b0.z,b0.w,b1.x,b1.y,b1.z,b1.w};
      #pragma unroll
      for (int i=0;i<4;i++)
        #pragma unroll
        for (int j=0;j<8;j++) acc[i][j] += av[i]*bv[j];
    }
    __syncthreads();
  }
  int tl = nt - n0; if (tl > TT) tl = TT;
  if (c0 < tl){
    float qnr[4];
    #pragma unroll
    for (int i=0;i<4;i++) qnr[i]=qn[qbase+r0+i];
    float tnv[8]; unsigned labv[8];
    #pragma unroll
    for (int j=0;j<8;j++){ int g=n0+c0+j; tnv[j]=tn[g]; labv[j]=(unsigned)labels[g]; }
    #pragma unroll
    for (int i=0;i<4;i++){
      unsigned kk[8];
      #pragma unroll
      for (int j=0;j<8;j++){
        float d2 = fmaxf(qnr[i] - 2.f*acc[i][j] + tnv[j], 0.f);
        kk[j] = (__float_as_uint(d2)&0xFFFFFFF8u) | labv[j];
      }
      unsigned* dst = &keys[(size_t)(qbase+r0+i)*nt + n0+c0];
      *(uint4*)dst     = make_uint4(kk[0],kk[1],kk[2],kk[3]);
      *(uint4*)(dst+4) = make_uint4(kk[4],kk[5],kk[6],kk[7]);
    }
  }
}

// ---------------- scan helper: find bin containing rank Krem ------------------
__device__ __forceinline__ void find_bin(int* hist, int* part, int nb, int Krem,
                                         int tid, int* s_B, int* s_lob){
  int ch = nb>>8;
  int s=0;
  for (int b=tid*ch;b<tid*ch+ch;b++) s+=hist[b];
  part[tid]=s;
  __syncthreads();
  if (tid==0){
    int cum=0, B=nb-1, lob=0;
    for (int t=0;t<256;t++){
      if (cum+part[t] >= Krem){
        lob=cum;
        for (int b=t*ch;b<t*ch+ch;b++){
          if (lob+hist[b]>=Krem){ B=b; break; }
          lob+=hist[b];
        }
        break;
      }
      cum+=part[t];
    }
    *s_B=B; *s_lob=lob;
  }
  __syncthreads();
}

// ---------------- per-query threshold: exact RSEL-th smallest sample key ------
__global__ __launch_bounds__(256) void sel64_k(const unsigned* __restrict__ skeys,
                                               unsigned* __restrict__ Tthr){
  __shared__ unsigned buf[NSUB];
  __shared__ int hist[2048];
  __shared__ int part[256];
  __shared__ int sB, sLob;
  int tid=threadIdx.x, q=blockIdx.x;
  for (int i=tid;i<NSUB;i+=256) buf[i]=skeys[(size_t)q*NSUB+i];
  int Krem=RSEL;
  for (int i=tid;i<2048;i+=256) hist[i]=0;
  __syncthreads();
  for (int i=tid;i<NSUB;i+=256) atomicAdd(&hist[buf[i]>>21],1);
  __syncthreads();
  find_bin(hist,part,2048,Krem,tid,&sB,&sLob);
  unsigned pre=(unsigned)sB; Krem-=sLob;
  for (int i=tid;i<2048;i+=256) hist[i]=0;
  __syncthreads();
  for (int i=tid;i<NSUB;i+=256){ unsigned k=buf[i]; if ((k>>21)==pre) atomicAdd(&hist[(k>>10)&0x7FFu],1); }
  __syncthreads();
  find_bin(hist,part,2048,Krem,tid,&sB,&sLob);
  pre=(pre<<11)|(unsigned)sB; Krem-=sLob;
  for (int i=tid;i<1024;i+=256) hist[i]=0;
  __syncthreads();
  for (int i=tid;i<NSUB;i+=256){ unsigned k=buf[i]; if ((k>>10)==pre) atomicAdd(&hist[k&0x3FFu],1); }
  __syncthreads();
  find_bin(hist,part,1024,Krem,tid,&sB,&sLob);
  if (tid==0) Tthr[q]=(pre<<10)|(unsigned)sB;
}

// ---------------- MFMA split-bf16 distance GEMM, LDS-staged B, 256q tile ------
// 1D grid of 8*4*49=1568 blocks, XCD-swizzled (b&7 = stripe). Block = 256q x 128t.
// 2x MFMA per staged B chunk vs the 128q tile; half the barriers per FLOP.
__global__ __launch_bounds__(256) void dist_mfma_k(
    const unsigned short* __restrict__ QH, const unsigned short* __restrict__ QL,
    const unsigned short* __restrict__ TH, const unsigned short* __restrict__ TL,
    const float* __restrict__ qn, const float* __restrict__ tn,
    const int* __restrict__ labels, const unsigned* __restrict__ Tthr,
    unsigned* __restrict__ slab, int dp)
{
  __shared__ unsigned short BH[128*32];   // 8 KB
  __shared__ unsigned short BL[128*32];   // 8 KB
  __shared__ unsigned hitbuf[256][SLOTS]; // 16 KB
  __shared__ int hcnt[256];
  int b = blockIdx.x;
  int xcd = b & 7, s = b >> 3;
  int qb = s & 3, tslot = s >> 2;
  int t_blk = xcd + 8*tslot;
  if (t_blk >= NTB) return;
  int tid = threadIdx.x, w = tid>>6, lane = tid&63;
  int quad = lane>>4, col = lane&15;
  int qbase = qb*256;
  int n0 = t_blk*TT;
  int kchunks = dp >> 5;

  // A per-lane base (element units): wave w owns q rows [qbase+w*64, +64)
  size_t aoff = (size_t)(qbase + w*64 + col)*dp + quad*8;
  const unsigned short* pAH = QH + aoff;
  const unsigned short* pAL = QL + aoff;
  size_t qi_step = (size_t)16*dp;

  // staging source offsets (global side swizzled so fragment reads are 2-way)
  int i0 = tid,      row0 = i0>>2, sg0 = ((i0&3) - (row0>>1)) & 3;
  int i1 = tid+256,  row1 = i1>>2, sg1 = ((i1&3) - (row1>>1)) & 3;
  size_t g0 = (size_t)(n0+row0)*dp + (size_t)sg0*8;
  size_t g1 = (size_t)(n0+row1)*dp + (size_t)sg1*8;

  f32x4 acc[4][8];
  #pragma unroll
  for (int qi=0;qi<4;qi++)
    #pragma unroll
    for (int tj=0;tj<8;tj++){ f32x4 z={0.f,0.f,0.f,0.f}; acc[qi][tj]=z; }

  for (int kc=0;kc<kchunks;kc++){
    size_t ko = (size_t)kc*32;
    __syncthreads();   // protect LDS reuse from previous chunk's readers
    gl_lds16(TH + g0 + ko, &BH[i0*8]);
    gl_lds16(TH + g1 + ko, &BH[i1*8]);
    gl_lds16(TL + g0 + ko, &BL[i0*8]);
    gl_lds16(TL + g1 + ko, &BL[i1*8]);
    // A loads overlap the staging latency
    bf16x8 ah[4], al[4];
    #pragma unroll
    for (int qi=0;qi<4;qi++){
      ah[qi] = ld8(pAH + (size_t)qi*qi_step + ko);
      al[qi] = ld8(pAL + (size_t)qi*qi_step + ko);
    }
    __syncthreads();   // drains vmcnt (staging + A) before fragment reads
    #pragma unroll
    for (int tj=0;tj<8;tj++){
      int rowB = tj*16 + col;
      int sw = (((quad + (rowB>>1)) & 3) << 3);
      bf16x8 bh = *(const bf16x8*)&BH[rowB*32 + sw];
      bf16x8 bl = *(const bf16x8*)&BL[rowB*32 + sw];
      #pragma unroll
      for (int qi=0;qi<4;qi++){
        acc[qi][tj] = __builtin_amdgcn_mfma_f32_16x16x32_bf16(ah[qi], bh, acc[qi][tj], 0,0,0);
        acc[qi][tj] = __builtin_amdgcn_mfma_f32_16x16x32_bf16(ah[qi], bl, acc[qi][tj], 0,0,0);
        acc[qi][tj] = __builtin_amdgcn_mfma_f32_16x16x32_bf16(al[qi], bh, acc[qi][tj], 0,0,0);
      }
    }
  }

  // epilogue: d2 from norms + acc, threshold compare, LDS slab compaction
  hcnt[tid]=0;
  __syncthreads();
  float qnr[4][4]; unsigned Tq[4][4];
  #pragma unroll
  for (int qi=0;qi<4;qi++)
    #pragma unroll
    for (int r=0;r<4;r++){
      int q = qbase + w*64 + qi*16 + quad*4 + r;
      qnr[qi][r] = qn[q];
      Tq[qi][r]  = Tthr[q];
    }
  #pragma unroll
  for (int tj=0;tj<8;tj++){
    int t = n0 + tj*16 + col;
    if (t < NT){
      float tnv = tn[t];
      unsigned lab = (unsigned)labels[t];
      #pragma unroll
      for (int qi=0;qi<4;qi++)
        #pragma unroll
        for (int r=0;r<4;r++){
          float d2 = fmaxf(qnr[qi][r] - 2.f*acc[qi][tj][r] + tnv, 0.f);
          unsigned key = (__float_as_uint(d2)&0xFFFFFFF8u) | lab;
          if (key < Tq[qi][r]){
            int ql = w*64 + qi*16 + quad*4 + r;
            int idx = atomicAdd(&hcnt[ql], 1);
            if (idx < SLOTS-1) hitbuf[ql][1+idx] = key;
          }
        }
    }
  }
  __syncthreads();
  hitbuf[tid][0]=(unsigned)hcnt[tid];
  __syncthreads();
  // dump 256 slabs x 16 words: 1024 uint4 stores over 256 threads
  #pragma unroll
  for (int rep=0; rep<4; rep++){
    int idx = rep*256 + tid;
    int q = idx>>2, sub = (idx&3)*4;
    uint4 v = *(uint4*)&hitbuf[q][sub];
    *(uint4*)&slab[((size_t)(qbase+q)*NTB + t_blk)*SLOTS + sub] = v;
  }
}

// ---------------- gather slabs (coalesced via LDS), exact radix select --------
__global__ __launch_bounds__(256) void final_k(
    const unsigned* __restrict__ slab,
    const float* __restrict__ Qm, const float* __restrict__ Tm,
    const float* __restrict__ qn, const float* __restrict__ tn,
    const int* __restrict__ labels,
    float* __restrict__ tot, int first, int dp)
{
  __shared__ int hist[2048];
  __shared__ int part[256];
  __shared__ unsigned buf[CAP];
  __shared__ unsigned lowbuf[96];
  __shared__ float qrow[128];
  __shared__ uint4 stg[1024];     // 16 KB coalesced staging (256 slabs/chunk)
  __shared__ int sB,sLob,s_cnt,s_low,s_bad;
  __shared__ float s_w[9];
  int tid=threadIdx.x, q=blockIdx.x;
  if (tid==0){ for (int j=0;j<9;j++) s_w[j]=0.f; s_cnt=0; s_low=0; s_bad=0; }
  __syncthreads();

  // gather candidates: stage 256 slabs at a time with fully-coalesced uint4 reads
  const unsigned* sq = slab + (size_t)q*NTB*SLOTS;
  for (int cb=0; cb<NTB; cb+=256){
    int nm = NTB-cb; if (nm>256) nm=256;
    __syncthreads();
    const uint4* gsrc = (const uint4*)(sq + (size_t)cb*SLOTS);
    for (int i=tid; i<nm*4; i+=256) stg[i]=gsrc[i];
    __syncthreads();
    for (int sidx=tid; sidx<nm; sidx+=256){
      uint4 a = stg[sidx*4];
      unsigned cnt = a.x;
      if (cnt > SLOTS-1){ s_bad=1; continue; }
      if (!cnt) continue;
      int base = atomicAdd(&s_cnt, (int)cnt);
      if (base + (int)cnt <= CAP){
        buf[base] = a.y;
        if (cnt>=2) buf[base+1] = a.z;
        if (cnt>=3) buf[base+2] = a.w;
        if (cnt>=4){
          const unsigned* tw = (const unsigned*)&stg[sidx*4+1];
          for (unsigned w2=4; w2<=cnt; w2++) buf[base+w2-1] = tw[w2-4];
        }
      }
    }
  }
  __syncthreads();
  int total = s_cnt;
  int bad = s_bad;

#define CONTRIB(kk) do{ float d2_=__uint_as_float((kk)&0xFFFFFFF8u); \
    if (d2_>0.f){ float w_=1.0f/sqrtf(d2_); \
      atomicAdd(&s_w[8],w_); atomicAdd(&s_w[(kk)&7u],w_); } }while(0)

  unsigned T; int Krem=KNN;
  if (!bad && total>=KNN && total<=CAP){
    for (int i=tid;i<2048;i+=256) hist[i]=0;
    __syncthreads();
    for (int i=tid;i<total;i+=256) atomicAdd(&hist[buf[i]>>21],1);
    __syncthreads();
    find_bin(hist,part,2048,Krem,tid,&sB,&sLob);
    unsigned pre=(unsigned)sB; Krem-=sLob;
    for (int i=tid;i<2048;i+=256) hist[i]=0;
    __syncthreads();
    for (int i=tid;i<total;i+=256){ unsigned k=buf[i]; if ((k>>21)==pre) atomicAdd(&hist[(k>>10)&0x7FFu],1); }
    __syncthreads();
    find_bin(hist,part,2048,Krem,tid,&sB,&sLob);
    pre=(pre<<11)|(unsigned)sB; Krem-=sLob;
    for (int i=tid;i<1024;i+=256) hist[i]=0;
    __syncthreads();
    for (int i=tid;i<total;i+=256){ unsigned k=buf[i]; if ((k>>10)==pre) atomicAdd(&hist[k&0x3FFu],1); }
    __syncthreads();
    find_bin(hist,part,1024,Krem,tid,&sB,&sLob);
    T=(pre<<10)|(unsigned)sB; Krem-=sLob;
    __syncthreads();
    for (int i=tid;i<total;i+=256){ unsigned k=buf[i]; if (k<T) CONTRIB(k); }
  } else {
    // fallback (P ~ 1e-10): exact fp32 full recompute select
    if (tid==0) s_cnt=0;
    for (int i=tid;i<dp;i+=256) qrow[i]=Qm[(size_t)q*dp+i];
    __syncthreads();
    float qq=qn[q];
    auto KEY=[&](int t)->unsigned{
      const float* br=&Tm[(size_t)t*dp];
      float dot=0.f;
      for (int k2=0;k2<dp;k2++) dot+=qrow[k2]*br[k2];
      float d2=fmaxf(qq-2.f*dot+tn[t],0.f);
      return (__float_as_uint(d2)&0xFFFFFFF8u)|(unsigned)labels[t];
    };
    for (int i=tid;i<2048;i+=256) hist[i]=0;
    __syncthreads();
    for (int t=tid;t<NT;t+=256) atomicAdd(&hist[KEY(t)>>21],1);
    __syncthreads();
    find_bin(hist,part,2048,Krem,tid,&sB,&sLob);
    int c=hist[sB]; Krem-=sLob;
    unsigned prefix=(unsigned)sB; int shift=21;
    if (c > CAP){
      __syncthreads();
      for (int i=tid;i<2048;i+=256) hist[i]=0;
      __syncthreads();
      for (int t=tid;t<NT;t+=256){ unsigned k=KEY(t); if ((k>>21)==prefix) atomicAdd(&hist[(k>>10)&0x7FFu],1); }
      __syncthreads();
      find_bin(hist,part,2048,Krem,tid,&sB,&sLob);
      c=hist[sB]; Krem-=sLob; prefix=(prefix<<11)|(unsigned)sB; shift=10;
    }
    if (c > CAP){
      __syncthreads();
      for (int i=tid;i<1024;i+=256) hist[i]=0;
      __syncthreads();
      for (int t=tid;t<NT;t+=256){ unsigned k=KEY(t); if ((k>>10)==prefix) atomicAdd(&hist[k&0x3FFu],1); }
      __syncthreads();
      find_bin(hist,part,1024,Krem,tid,&sB,&sLob);
      c=hist[sB]; Krem-=sLob; prefix=(prefix<<10)|(unsigned)sB; shift=0;
    }
    if (c <= CAP){
      for (int t=tid;t<NT;t+=256){
        unsigned k=KEY(t); unsigned pp=k>>shift;
        if (pp==prefix){ int j=atomicAdd(&s_cnt,1); if (j<CAP) buf[j]=k; }
        else if (pp<prefix){ int j=atomicAdd(&s_low,1); if (j<96) lowbuf[j]=k; }
      }
      __syncthreads();
      int sh=shift;
      while (sh>0){
        int nsh=(sh==21)?10:0;
        int nb=1<<(sh-nsh);
        __syncthreads();
        for (int i=tid;i<nb;i+=256) hist[i]=0;
        __syncthreads();
        int cc=s_cnt;
        for (int i=tid;i<cc;i+=256) atomicAdd(&hist[(buf[i]>>nsh)&(unsigned)(nb-1)],1);
        __syncthreads();
        find_bin(hist,part,nb,Krem,tid,&sB,&sLob);
        Krem-=sLob; prefix=(prefix<<(sh-nsh))|(unsigned)sB; sh=nsh;
      }
      T=prefix;
      __syncthreads();
      int lowc=s_low, cc=s_cnt;
      for (int i=tid;i<lowc;i+=256){ unsigned k=lowbuf[i]; CONTRIB(k); }
      for (int i=tid;i<cc;i+=256){ unsigned k=buf[i]; if (k<T) CONTRIB(k); }
    } else {
      T=prefix;
      for (int t=tid;t<NT;t+=256){ unsigned k=KEY(t); if (k<T) CONTRIB(k); }
    }
  }
  __syncthreads();
  if (tid==0){
    float d2=__uint_as_float(T&0xFFFFFFF8u);
    float w=(d2>0.f)?(1.0f/sqrtf(d2)):0.f;
    s_w[8] += (float)Krem*w;
    s_w[T&7u] += (float)Krem*w;
  }
  __syncthreads();
  if (tid<8){
    float contrib = s_w[8]-s_w[tid];
    size_t o=(size_t)q*NL+tid;
    tot[o] = first ? contrib : tot[o]+contrib;
  }
#undef CONTRIB
}

// ---------------- empirical p-values ------------------------------------------
__global__ void pvalue_k(const float* __restrict__ tot, const float* __restrict__ cali,
                         float* __restrict__ out){
  __shared__ float t8[NL];
  __shared__ int part[4][NL];
  int tid=threadIdx.x, q=blockIdx.x;
  if (tid<NL) t8[tid]=tot[(size_t)q*NL+tid];
  __syncthreads();
  float th[NL];
  #pragma unroll
  for (int c=0;c<NL;c++) th[c]=t8[c];
  int cnt[NL];
  #pragma unroll
  for (int c=0;c<NL;c++) cnt[c]=0;
  for (int i=tid;i<NCALI;i+=256){
    float v=cali[i];
    #pragma unroll
    for (int c=0;c<NL;c++) cnt[c] += (v>=th[c]) ? 1 : 0;
  }
  #pragma unroll
  for (int c=0;c<NL;c++){
    #pragma unroll
    for (int off=32;off>0;off>>=1) cnt[c]+=__shfl_down(cnt[c],off,64);
  }
  if ((tid&63)==0){
    #pragma unroll
    for (int c=0;c<NL;c++) part[tid>>6][c]=cnt[c];
  }
  __syncthreads();
  if (tid<NL){
    int s=part[0][tid]+part[1][tid]+part[2][tid]+part[3][tid];
    out[(size_t)q*NL+tid] = (float)s / 10000.f;
  }
}

extern "C" void kernel_launch(void* const* d_in, const int* in_sizes, int n_in,
                              void* d_out, int out_size, void* d_ws, size_t ws_size,
                              hipStream_t stream) {
  const float* x   = (const float*)d_in[0];
  const float* txr = (const float*)d_in[1];
  const int*   lbl = (const int*)  d_in[2];
  const float* cal = (const float*)d_in[3];
  const float* W1  = (const float*)d_in[4];
  const float* b1  = (const float*)d_in[5];
  const float* W2  = (const float*)d_in[6];
  const float* b2  = (const float*)d_in[7];
  const float* W3  = (const float*)d_in[8];
  const float* b3  = (const float*)d_in[9];
  const float* W4  = (const float*)d_in[10];
  const float* b4  = (const float*)d_in[11];
  float* out = (float*)d_out;
  float* ws  = (float*)d_ws;

  size_t off=0;
  float* xq0=ws+off; off+=(size_t)NB*96;
  float* xq1=ws+off; off+=(size_t)NB*128;
  float* xq2=ws+off; off+=(size_t)NB*128;
  float* xq3=ws+off; off+=(size_t)NB*128;
  float* xq4=ws+off; off+=(size_t)NB*32;
  float* tbA=ws+off; off+=(size_t)NT*128;
  float* tbB=ws+off; off+=(size_t)NT*128;
  float* tb4=ws+off; off+=(size_t)NT*32;
  float* qnb=ws+off; off+=(size_t)5*NB;
  float* tnb=ws+off; off+=(size_t)NT;
  float* Tsub=ws+off; off+=(size_t)NSUB*128;
  float* tnsub=ws+off; off+=(size_t)NSUB;
  float* tot=ws+off; off+=(size_t)NB*NL;
  unsigned* sT=(unsigned*)(ws+off); off+=NB;
  // per-layer query hi/lo (stride = layer dp), bank hi/lo (single rotating set)
  unsigned short* qsplit=(unsigned short*)(ws+off); off+=(size_t)5*2*NB*64;
  unsigned short* bankH=(unsigned short*)(ws+off); off+=(size_t)NT_PAD*64;
  unsigned short* bankL=(unsigned short*)(ws+off); off+=(size_t)NT_PAD*64;
  off=(off+3)&~(size_t)3;
  unsigned* slab=(unsigned*)(ws+off);   // NB*NTB*SLOTS = 25.6 MB
  unsigned* skeys=(unsigned*)(ws+off);  // NB*NSUB     =  8.4 MB (aliased)
  { size_t slab_sz=(size_t)NB*NTB*SLOTS, skey_sz=(size_t)NB*NSUB;
    off += (slab_sz > skey_sz ? slab_sz : skey_sz); }

  unsigned short* qH[5]; unsigned short* qL[5];
  for (int l=0;l<5;l++){
    qH[l]=qsplit + (size_t)l*2*NB*128;
    qL[l]=qH[l] + (size_t)NB*128;
  }

  // query features; layer-0 at stride 96. mlp_gemm fuses bf16-split + norms.
  pad_copy_k<<<(NB*96+255)/256,256,0,stream>>>(x, xq0, NB, 83, 96);
  pad_copy_k<<<((size_t)NT*96+255)/256,256,0,stream>>>(txr, tbA, NT, 83, 96);
  conv_norm_k<<<(NB+3)/4,256,0,stream>>>(xq0, qH[0], qL[0], qnb+0*NB, NB, 96);
  mlp_gemm_k<<<(NB+127)/128,256,0,stream>>>(xq0,96,3,W1,83,b1,xq1,qH[1],qL[1],qnb+1*NB,NB);
  mlp_gemm_k<<<(NB+127)/128,256,0,stream>>>(xq1,128,4,W2,128,b2,xq2,qH[2],qL[2],qnb+2*NB,NB);
  mlp_gemm_k<<<(NB+127)/128,256,0,stream>>>(xq2,128,4,W3,128,b3,xq3,qH[3],qL[3],qnb+3*NB,NB);
  mlp8_k<<<(NB+31)/32,256,0,stream>>>(xq3,W4,b4,xq4,NB);
  softmax_k<<<(NB+255)/256,256,0,stream>>>(xq4,NB);
  conv_norm_k<<<(NB+3)/4,256,0,stream>>>(xq4, qH[4], qL[4], qnb+4*NB, NB, 32);

  auto knn_layer = [&](const float* Qm, unsigned short* qh, unsigned short* ql,
                       const float* Bank, float* qnl, int dp, int first){
    sub_gather_k<<<(NSUB*dp+NSUB+255)/256,256,0,stream>>>(Bank,tnb,Tsub,tnsub,dp);
    dist_key_k<<<dim3(NB/QT,NSUB/TT),256,0,stream>>>(Qm,Tsub,qnl,tnsub,lbl,skeys,dp,NSUB);
    sel64_k<<<NB,256,0,stream>>>(skeys,sT);
    dist_mfma_k<<<8*4*49,256,0,stream>>>(qh,ql,bankH,bankL,qnl,tnb,lbl,sT,slab,dp);
    final_k<<<NB,256,0,stream>>>(slab,Qm,Bank,qnl,tnb,lbl,tot,first,dp);
  };

  // layer 0
  conv_norm_k<<<(NT+3)/4,256,0,stream>>>(tbA, bankH, bankL, tnb, NT, 96);
  knn_layer(xq0, qH[0], qL[0], tbA, qnb+0*NB, 96, 1);
  // layer 1 (mlp_gemm writes fp32 + bank hi/lo + tnb)
  mlp_gemm_k<<<(NT+127)/128,256,0,stream>>>(tbA,96,3,W1,83,b1,tbB,bankH,bankL,tnb,NT);
  knn_layer(xq1, qH[1], qL[1], tbB, qnb+1*NB, 128, 0);
  // layer 2
  mlp_gemm_k<<<(NT+127)/128,256,0,stream>>>(tbB,128,4,W2,128,b2,tbA,bankH,bankL,tnb,NT);
  knn_layer(xq2, qH[2], qL[2], tbA, qnb+2*NB, 128, 0);
  // layer 3
  mlp_gemm_k<<<(NT+127)/128,256,0,stream>>>(tbA,128,4,W3,128,b3,tbB,bankH,bankL,tnb,NT);
  knn_layer(xq3, qH[3], qL[3], tbB, qnb+3*NB, 128, 0);
  // layer 4
  mlp8_k<<<(NT+31)/32,256,0,stream>>>(tbB,W4,b4,tb4,NT);
  softmax_k<<<(NT+255)/256,256,0,stream>>>(tb4,NT);
  conv_norm_k<<<(NT+3)/4,256,0,stream>>>(tb4, bankH, bankL, tnb, NT, 32);
  knn_layer(xq4, qH[4], qL[4], tb4, qnb+4*NB, 32, 0);

  pvalue_k<<<NB,256,0,stream>>>(tot,cal,out);
}

// Round 11
// 1319.428 us; speedup vs baseline: 1.1584x; 1.1584x over previous
//
#include <hip/hip_runtime.h>
#include <math.h>

#define KNN 75
#define NL 8
#define NB 1024
#define NT 50000
#define NT_PAD 50048  // NTB*TT rows allocated for bf16 banks (pad rows masked)
#define NCALI 10000
#define KC 32
#define QT 64
#define TT 128
#define NTB 391       // ceil(NT/TT)
#define SLOTS 16      // per (q, t-block) slab: [count, up to 15 hit keys] = 64B
#define CAP 6144      // candidate buffer per query
#define NSUB 2048     // sampled train points for threshold
#define SSTRIDE 24
#define SOFF 11       // 11 + 24*2047 = 49139 < 50000
#define RSEL 32       // sample rank -> expected |{k < T}| ~ 780, lambda/slab ~ 2

typedef __attribute__((ext_vector_type(8))) short bf16x8;
typedef __attribute__((ext_vector_type(4))) float f32x4;

__device__ __forceinline__ int swz(int c){ return c + ((c>>5)<<2); }

__device__ __forceinline__ unsigned short f2bf_rn(float x){
  unsigned u = __float_as_uint(x);
  unsigned r = (u + 0x7FFFu + ((u>>16)&1u)) >> 16;
  return (unsigned short)r;
}
__device__ __forceinline__ float bf2f(unsigned short h){
  return __uint_as_float(((unsigned)h)<<16);
}
__device__ __forceinline__ bf16x8 ld8(const unsigned short* p){
  return *(const bf16x8*)p;
}
// async global->LDS, 16B per lane; LDS dest = wave-uniform base + lane*16
__device__ __forceinline__ void gl_lds16(const unsigned short* g, unsigned short* l){
  __builtin_amdgcn_global_load_lds(
      (const __attribute__((address_space(1))) void*)g,
      (__attribute__((address_space(3))) void*)l, 16, 0, 0);
}

// ---------------- pad copy (zero-fill pad cols every call: ws is poisoned) ----
__global__ void pad_copy_k(const float* __restrict__ in, float* __restrict__ out,
                           int M, int Din, int Dout){
  int idx = blockIdx.x*256 + threadIdx.x;
  if (idx >= M*Dout) return;
  int r = idx / Dout, c = idx - r*Dout;
  out[idx] = (c < Din) ? in[r*Din + c] : 0.f;
}

// ---------------- MLP GEMM: Out = relu(A@W+b), fused bf16-split + row norms ---
__global__ __launch_bounds__(256) void mlp_gemm_k(
    const float* __restrict__ A, int lda, int kchunks,
    const float* __restrict__ W, int kreal,
    const float* __restrict__ bias,
    float* __restrict__ Out,
    unsigned short* __restrict__ H, unsigned short* __restrict__ L,
    float* __restrict__ nrm, int M)
{
  __shared__ float As[KC][132];
  __shared__ float Bs[KC][148];
  __shared__ float nrm_s[128][17];
  int tid = threadIdx.x;
  int r0 = (tid>>4)*8, c0 = (tid&15)*8;
  int rowBase = blockIdx.x*128;
  float acc[8][8];
  #pragma unroll
  for (int i=0;i<8;i++)
    #pragma unroll
    for (int j=0;j<8;j++) acc[i][j]=0.f;

  for (int kc=0;kc<kchunks;kc++){
    { int rr = tid>>3, k4=(tid&7)*4;
      #pragma unroll
      for (int i=0;i<4;i++){
        int row = rr + i*32, gr = rowBase + row;
        float4 v = make_float4(0.f,0.f,0.f,0.f);
        if (gr < M) v = *(const float4*)&A[(size_t)gr*lda + kc*KC + k4];
        As[k4+0][row]=v.x; As[k4+1][row]=v.y; As[k4+2][row]=v.z; As[k4+3][row]=v.w;
      }
    }
    { int kk=tid>>5, c4=(tid&31)*4;
      #pragma unroll
      for (int i=0;i<4;i++){
        int k = kk + i*8, gk = kc*KC + k;
        float4 v = make_float4(0.f,0.f,0.f,0.f);
        if (gk < kreal) v = *(const float4*)&W[(size_t)gk*128 + c4];
        *(float4*)&Bs[k][swz(c4)] = v;
      }
    }
    __syncthreads();
    #pragma unroll 4
    for (int k=0;k<KC;k++){
      float4 a0 = *(const float4*)&As[k][r0];
      float4 a1 = *(const float4*)&As[k][r0+4];
      float4 b0 = *(const float4*)&Bs[k][swz(c0)];
      float4 b1 = *(const float4*)&Bs[k][swz(c0+4)];
      float av[8] = {a0.x,a0.y,a0.z,a0.w,a1.x,a1.y,a1.z,a1.w};
      float bv[8] = {b0.x,b0.y,b0.z,b0.w,b1.x,b1.y,b1.z,b1.w};
      #pragma unroll
      for (int i=0;i<8;i++)
        #pragma unroll
        for (int j=0;j<8;j++) acc[i][j] += av[i]*bv[j];
    }
    __syncthreads();
  }
  float bb[8];
  #pragma unroll
  for (int j=0;j<8;j++) bb[j]=bias[c0+j];
  #pragma unroll
  for (int i=0;i<8;i++){
    int gr = rowBase + r0 + i;
    float o[8]; float part=0.f;
    #pragma unroll
    for (int j=0;j<8;j++){
      float v=acc[i][j]+bb[j]; v = v>0.f?v:0.f; o[j]=v; part += v*v;
    }
    nrm_s[r0+i][tid&15] = part;
    if (gr < M){
      *(float4*)&Out[(size_t)gr*128 + c0]   = make_float4(o[0],o[1],o[2],o[3]);
      *(float4*)&Out[(size_t)gr*128 + c0+4] = make_float4(o[4],o[5],o[6],o[7]);
      unsigned short hh[8], ll[8];
      #pragma unroll
      for (int j=0;j<8;j++){
        unsigned short h = f2bf_rn(o[j]);
        hh[j]=h; ll[j]=f2bf_rn(o[j]-bf2f(h));
      }
      *(uint4*)&H[(size_t)gr*128 + c0] = *(uint4*)hh;
      *(uint4*)&L[(size_t)gr*128 + c0] = *(uint4*)ll;
    }
  }
  __syncthreads();
  if (tid < 128){
    int gr = rowBase + tid;
    if (gr < M){
      float s=0.f;
      #pragma unroll
      for (int cg=0;cg<16;cg++) s += nrm_s[tid][cg];
      nrm[gr]=s;
    }
  }
}

// ---------------- last layer: logits[M][8] into stride-32 rows ----------------
__global__ void mlp8_k(const float* __restrict__ A, const float* __restrict__ W4,
                       const float* __restrict__ b4, float* __restrict__ Out, int M){
  __shared__ float Ws[128*8];
  int tid = threadIdx.x;
  for (int i=tid;i<1024;i+=256) Ws[i]=W4[i];
  __syncthreads();
  int r = blockIdx.x*32 + (tid>>3), c = tid&7;
  if (r >= M) return;
  const float* a = &A[(size_t)r*128];
  float acc = b4[c];
  #pragma unroll 16
  for (int k=0;k<128;k++) acc += a[k]*Ws[k*8+c];
  Out[(size_t)r*32 + c] = acc;
}

// ---------------- softmax over 8 logits, zero cols 8..31 ----------------------
__global__ void softmax_k(float* __restrict__ X, int M){
  int r = blockIdx.x*256 + threadIdx.x;
  if (r >= M) return;
  float* p = &X[(size_t)r*32];
  float v[8], m=-1e30f;
  #pragma unroll
  for (int j=0;j<8;j++){ v[j]=p[j]; m = v[j]>m ? v[j] : m; }
  float s=0.f;
  #pragma unroll
  for (int j=0;j<8;j++){ v[j]=__expf(v[j]-m); s+=v[j]; }
  float inv=1.f/s;
  #pragma unroll
  for (int j=0;j<8;j++) p[j]=v[j]*inv;
  #pragma unroll
  for (int j=8;j<32;j++) p[j]=0.f;
}

// ---------------- fp32 -> (hi,lo) bf16 split + row squared-norms --------------
__global__ void conv_norm_k(const float* __restrict__ X,
                            unsigned short* __restrict__ H,
                            unsigned short* __restrict__ L,
                            float* __restrict__ nrm, int M, int dp){
  int w = threadIdx.x>>6, lane = threadIdx.x&63;
  int row = blockIdx.x*4 + w;
  if (row >= M) return;
  const float* src = &X[(size_t)row*dp];
  unsigned short* dh = &H[(size_t)row*dp];
  unsigned short* dl = &L[(size_t)row*dp];
  float s=0.f;
  for (int c=lane;c<dp;c+=64){
    float v = src[c];
    s += v*v;
    unsigned short h = f2bf_rn(v);
    float rem = v - bf2f(h);
    dh[c] = h;
    dl[c] = f2bf_rn(rem);
  }
  #pragma unroll
  for (int off=32;off>0;off>>=1) s += __shfl_down(s, off, 64);
  if (lane==0) nrm[row]=s;
}

// ---------------- gather sampled subset bank + its norms ----------------------
__global__ void sub_gather_k(const float* __restrict__ Bank, const float* __restrict__ tnb,
                             float* __restrict__ Tsub, float* __restrict__ tnsub, int dp){
  int idx = blockIdx.x*256 + threadIdx.x;
  int total = NSUB*dp;
  if (idx < total){
    int s = idx/dp, c = idx - s*dp;
    Tsub[idx] = Bank[(size_t)(s*SSTRIDE+SOFF)*dp + c];
  } else if (idx < total + NSUB){
    int s = idx - total;
    tnsub[s] = tnb[s*SSTRIDE+SOFF];
  }
}

// ---------------- subset distance GEMM (fp32) -> packed keys ------------------
__global__ __launch_bounds__(256) void dist_key_k(
    const float* __restrict__ Qm, const float* __restrict__ Tm,
    const float* __restrict__ qn, const float* __restrict__ tn,
    const int* __restrict__ labels, unsigned* __restrict__ keys, int dp, int nt)
{
  __shared__ float qs[KC][68];
  __shared__ float ts[KC][148];
  int tid = threadIdx.x;
  int qbase = blockIdx.x*QT;
  int n0 = blockIdx.y*TT;
  int kchunks = dp >> 5;
  int r0 = (tid>>4)*4, c0=(tid&15)*8;
  float acc[4][8];
  #pragma unroll
  for (int i=0;i<4;i++)
    #pragma unroll
    for (int j=0;j<8;j++) acc[i][j]=0.f;

  for (int kc=0;kc<kchunks;kc++){
    { int qq0=tid>>3, k4=(tid&7)*4;
      #pragma unroll
      for (int i=0;i<2;i++){
        int qq=qq0+i*32;
        float4 v = *(const float4*)&Qm[(size_t)(qbase+qq)*dp + kc*KC + k4];
        qs[k4+0][qq]=v.x; qs[k4+1][qq]=v.y; qs[k4+2][qq]=v.z; qs[k4+3][qq]=v.w;
      }
    }
    { int tt0=tid>>3, k4=(tid&7)*4;
      #pragma unroll
      for (int i=0;i<4;i++){
        int ttI=tt0+i*32, g=n0+ttI;
        float4 v = make_float4(0.f,0.f,0.f,0.f);
        if (g < nt) v = *(const float4*)&Tm[(size_t)g*dp + kc*KC + k4];
        int o=swz(ttI);
        ts[k4+0][o]=v.x; ts[k4+1][o]=v.y; ts[k4+2][o]=v.z; ts[k4+3][o]=v.w;
      }
    }
    __syncthreads();
    #pragma unroll 8
    for (int k=0;k<KC;k++){
      float4 a  = *(const float4*)&qs[k][r0];
      float4 b0 = *(const float4*)&ts[k][swz(c0)];
      float4 b1 = *(const float4*)&ts[k][swz(c0+4)];
      float av[4]={a.x,a.y,a.z,a.w};
      float bv[8]={b0.x,b0.y,b0.z,b0.w,b1.x,b1.y,b1.z,b1.w};
      #pragma unroll
      for (int i=0;i<4;i++)
        #pragma unroll
        for (int j=0;j<8;j++) acc[i][j] += av[i]*bv[j];
    }
    __syncthreads();
  }
  int tl = nt - n0; if (tl > TT) tl = TT;
  if (c0 < tl){
    float qnr[4];
    #pragma unroll
    for (int i=0;i<4;i++) qnr[i]=qn[qbase+r0+i];
    float tnv[8]; unsigned labv[8];
    #pragma unroll
    for (int j=0;j<8;j++){ int g=n0+c0+j; tnv[j]=tn[g]; labv[j]=(unsigned)labels[g]; }
    #pragma unroll
    for (int i=0;i<4;i++){
      unsigned kk[8];
      #pragma unroll
      for (int j=0;j<8;j++){
        float d2 = fmaxf(qnr[i] - 2.f*acc[i][j] + tnv[j], 0.f);
        kk[j] = (__float_as_uint(d2)&0xFFFFFFF8u) | labv[j];
      }
      unsigned* dst = &keys[(size_t)(qbase+r0+i)*nt + n0+c0];
      *(uint4*)dst     = make_uint4(kk[0],kk[1],kk[2],kk[3]);
      *(uint4*)(dst+4) = make_uint4(kk[4],kk[5],kk[6],kk[7]);
    }
  }
}

// ---------------- scan helper: find bin containing rank Krem ------------------
__device__ __forceinline__ void find_bin(int* hist, int* part, int nb, int Krem,
                                         int tid, int* s_B, int* s_lob){
  int ch = nb>>8;
  int s=0;
  for (int b=tid*ch;b<tid*ch+ch;b++) s+=hist[b];
  part[tid]=s;
  __syncthreads();
  if (tid==0){
    int cum=0, B=nb-1, lob=0;
    for (int t=0;t<256;t++){
      if (cum+part[t] >= Krem){
        lob=cum;
        for (int b=t*ch;b<t*ch+ch;b++){
          if (lob+hist[b]>=Krem){ B=b; break; }
          lob+=hist[b];
        }
        break;
      }
      cum+=part[t];
    }
    *s_B=B; *s_lob=lob;
  }
  __syncthreads();
}

// ---------------- per-query threshold: exact RSEL-th smallest sample key ------
__global__ __launch_bounds__(256) void sel64_k(const unsigned* __restrict__ skeys,
                                               unsigned* __restrict__ Tthr){
  __shared__ unsigned buf[NSUB];
  __shared__ int hist[2048];
  __shared__ int part[256];
  __shared__ int sB, sLob;
  int tid=threadIdx.x, q=blockIdx.x;
  for (int i=tid;i<NSUB;i+=256) buf[i]=skeys[(size_t)q*NSUB+i];
  int Krem=RSEL;
  for (int i=tid;i<2048;i+=256) hist[i]=0;
  __syncthreads();
  for (int i=tid;i<NSUB;i+=256) atomicAdd(&hist[buf[i]>>21],1);
  __syncthreads();
  find_bin(hist,part,2048,Krem,tid,&sB,&sLob);
  unsigned pre=(unsigned)sB; Krem-=sLob;
  for (int i=tid;i<2048;i+=256) hist[i]=0;
  __syncthreads();
  for (int i=tid;i<NSUB;i+=256){ unsigned k=buf[i]; if ((k>>21)==pre) atomicAdd(&hist[(k>>10)&0x7FFu],1); }
  __syncthreads();
  find_bin(hist,part,2048,Krem,tid,&sB,&sLob);
  pre=(pre<<11)|(unsigned)sB; Krem-=sLob;
  for (int i=tid;i<1024;i+=256) hist[i]=0;
  __syncthreads();
  for (int i=tid;i<NSUB;i+=256){ unsigned k=buf[i]; if ((k>>10)==pre) atomicAdd(&hist[k&0x3FFu],1); }
  __syncthreads();
  find_bin(hist,part,1024,Krem,tid,&sB,&sLob);
  if (tid==0) Tthr[q]=(pre<<10)|(unsigned)sB;
}

// ---------------- MFMA split-bf16 distance GEMM, LDS-staged B, 128q tile ------
// (round-9 proven config: VGPR ~88, grid 8*8*49, XCD-swizzled stripes)
__global__ __launch_bounds__(256) void dist_mfma_k(
    const unsigned short* __restrict__ QH, const unsigned short* __restrict__ QL,
    const unsigned short* __restrict__ TH, const unsigned short* __restrict__ TL,
    const float* __restrict__ qn, const float* __restrict__ tn,
    const int* __restrict__ labels, const unsigned* __restrict__ Tthr,
    unsigned* __restrict__ slab, int dp)
{
  __shared__ unsigned short BH[128*32];   // 8 KB
  __shared__ unsigned short BL[128*32];   // 8 KB
  __shared__ unsigned hitbuf[128][SLOTS];
  __shared__ int hcnt[128];
  int b = blockIdx.x;
  int xcd = b & 7, s = b >> 3;
  int qb = s & 7, tslot = s >> 3;
  int t_blk = xcd + 8*tslot;
  if (t_blk >= NTB) return;
  int tid = threadIdx.x, w = tid>>6, lane = tid&63;
  int quad = lane>>4, col = lane&15;
  int qbase = qb*128;
  int n0 = t_blk*TT;
  int kchunks = dp >> 5;

  size_t aoff = (size_t)(qbase + w*32 + col)*dp + quad*8;
  const unsigned short* pAH = QH + aoff;
  const unsigned short* pAL = QL + aoff;
  size_t qi_step = (size_t)16*dp;

  int i0 = tid,      row0 = i0>>2, sg0 = ((i0&3) - (row0>>1)) & 3;
  int i1 = tid+256,  row1 = i1>>2, sg1 = ((i1&3) - (row1>>1)) & 3;
  size_t g0 = (size_t)(n0+row0)*dp + (size_t)sg0*8;
  size_t g1 = (size_t)(n0+row1)*dp + (size_t)sg1*8;

  f32x4 acc[2][8];
  #pragma unroll
  for (int qi=0;qi<2;qi++)
    #pragma unroll
    for (int tj=0;tj<8;tj++){ f32x4 z={0.f,0.f,0.f,0.f}; acc[qi][tj]=z; }

  for (int kc=0;kc<kchunks;kc++){
    size_t ko = (size_t)kc*32;
    __syncthreads();
    gl_lds16(TH + g0 + ko, &BH[i0*8]);
    gl_lds16(TH + g1 + ko, &BH[i1*8]);
    gl_lds16(TL + g0 + ko, &BL[i0*8]);
    gl_lds16(TL + g1 + ko, &BL[i1*8]);
    bf16x8 a0h = ld8(pAH + ko);
    bf16x8 a0l = ld8(pAL + ko);
    bf16x8 a1h = ld8(pAH + qi_step + ko);
    bf16x8 a1l = ld8(pAL + qi_step + ko);
    __syncthreads();
    #pragma unroll
    for (int tj=0;tj<8;tj++){
      int rowB = tj*16 + col;
      int sw = (((quad + (rowB>>1)) & 3) << 3);
      bf16x8 bh = *(const bf16x8*)&BH[rowB*32 + sw];
      bf16x8 bl = *(const bf16x8*)&BL[rowB*32 + sw];
      acc[0][tj] = __builtin_amdgcn_mfma_f32_16x16x32_bf16(a0h, bh, acc[0][tj], 0,0,0);
      acc[0][tj] = __builtin_amdgcn_mfma_f32_16x16x32_bf16(a0h, bl, acc[0][tj], 0,0,0);
      acc[0][tj] = __builtin_amdgcn_mfma_f32_16x16x32_bf16(a0l, bh, acc[0][tj], 0,0,0);
      acc[1][tj] = __builtin_amdgcn_mfma_f32_16x16x32_bf16(a1h, bh, acc[1][tj], 0,0,0);
      acc[1][tj] = __builtin_amdgcn_mfma_f32_16x16x32_bf16(a1h, bl, acc[1][tj], 0,0,0);
      acc[1][tj] = __builtin_amdgcn_mfma_f32_16x16x32_bf16(a1l, bh, acc[1][tj], 0,0,0);
    }
  }

  if (tid<128) hcnt[tid]=0;
  __syncthreads();
  float qnr[2][4]; unsigned Tq[2][4];
  #pragma unroll
  for (int qi=0;qi<2;qi++)
    #pragma unroll
    for (int r=0;r<4;r++){
      int q = qbase + w*32 + qi*16 + quad*4 + r;
      qnr[qi][r] = qn[q];
      Tq[qi][r]  = Tthr[q];
    }
  #pragma unroll
  for (int tj=0;tj<8;tj++){
    int t = n0 + tj*16 + col;
    if (t < NT){
      float tnv = tn[t];
      unsigned lab = (unsigned)labels[t];
      #pragma unroll
      for (int qi=0;qi<2;qi++)
        #pragma unroll
        for (int r=0;r<4;r++){
          float d2 = fmaxf(qnr[qi][r] - 2.f*acc[qi][tj][r] + tnv, 0.f);
          unsigned key = (__float_as_uint(d2)&0xFFFFFFF8u) | lab;
          if (key < Tq[qi][r]){
            int ql = w*32 + qi*16 + quad*4 + r;
            int idx = atomicAdd(&hcnt[ql], 1);
            if (idx < SLOTS-1) hitbuf[ql][1+idx] = key;
          }
        }
    }
  }
  __syncthreads();
  if (tid<128) hitbuf[tid][0]=(unsigned)hcnt[tid];
  __syncthreads();
  #pragma unroll
  for (int rep=0; rep<2; rep++){
    int idx = rep*256 + tid;
    int q = idx>>2, sub = (idx&3)*4;
    uint4 v = *(uint4*)&hitbuf[q][sub];
    *(uint4*)&slab[((size_t)(qbase+q)*NTB + t_blk)*SLOTS + sub] = v;
  }
}

// ---------------- gather slabs (coalesced via LDS), exact radix select --------
__global__ __launch_bounds__(256) void final_k(
    const unsigned* __restrict__ slab,
    const float* __restrict__ Qm, const float* __restrict__ Tm,
    const float* __restrict__ qn, const float* __restrict__ tn,
    const int* __restrict__ labels,
    float* __restrict__ tot, int first, int dp)
{
  __shared__ int hist[2048];
  __shared__ int part[256];
  __shared__ unsigned buf[CAP];
  __shared__ unsigned lowbuf[96];
  __shared__ float qrow[128];
  __shared__ uint4 stg[1024];     // 16 KB coalesced staging (256 slabs/chunk)
  __shared__ int sB,sLob,s_cnt,s_low,s_bad;
  __shared__ float s_w[9];
  int tid=threadIdx.x, q=blockIdx.x;
  if (tid==0){ for (int j=0;j<9;j++) s_w[j]=0.f; s_cnt=0; s_low=0; s_bad=0; }
  __syncthreads();

  const unsigned* sq = slab + (size_t)q*NTB*SLOTS;
  for (int cb=0; cb<NTB; cb+=256){
    int nm = NTB-cb; if (nm>256) nm=256;
    __syncthreads();
    const uint4* gsrc = (const uint4*)(sq + (size_t)cb*SLOTS);
    for (int i=tid; i<nm*4; i+=256) stg[i]=gsrc[i];
    __syncthreads();
    for (int sidx=tid; sidx<nm; sidx+=256){
      uint4 a = stg[sidx*4];
      unsigned cnt = a.x;
      if (cnt > SLOTS-1){ s_bad=1; continue; }
      if (!cnt) continue;
      int base = atomicAdd(&s_cnt, (int)cnt);
      if (base + (int)cnt <= CAP){
        buf[base] = a.y;
        if (cnt>=2) buf[base+1] = a.z;
        if (cnt>=3) buf[base+2] = a.w;
        if (cnt>=4){
          const unsigned* tw = (const unsigned*)&stg[sidx*4+1];
          for (unsigned w2=4; w2<=cnt; w2++) buf[base+w2-1] = tw[w2-4];
        }
      }
    }
  }
  __syncthreads();
  int total = s_cnt;
  int bad = s_bad;

#define CONTRIB(kk) do{ float d2_=__uint_as_float((kk)&0xFFFFFFF8u); \
    if (d2_>0.f){ float w_=1.0f/sqrtf(d2_); \
      atomicAdd(&s_w[8],w_); atomicAdd(&s_w[(kk)&7u],w_); } }while(0)

  unsigned T; int Krem=KNN;
  if (!bad && total>=KNN && total<=CAP){
    for (int i=tid;i<2048;i+=256) hist[i]=0;
    __syncthreads();
    for (int i=tid;i<total;i+=256) atomicAdd(&hist[buf[i]>>21],1);
    __syncthreads();
    find_bin(hist,part,2048,Krem,tid,&sB,&sLob);
    unsigned pre=(unsigned)sB; Krem-=sLob;
    for (int i=tid;i<2048;i+=256) hist[i]=0;
    __syncthreads();
    for (int i=tid;i<total;i+=256){ unsigned k=buf[i]; if ((k>>21)==pre) atomicAdd(&hist[(k>>10)&0x7FFu],1); }
    __syncthreads();
    find_bin(hist,part,2048,Krem,tid,&sB,&sLob);
    pre=(pre<<11)|(unsigned)sB; Krem-=sLob;
    for (int i=tid;i<1024;i+=256) hist[i]=0;
    __syncthreads();
    for (int i=tid;i<total;i+=256){ unsigned k=buf[i]; if ((k>>10)==pre) atomicAdd(&hist[k&0x3FFu],1); }
    __syncthreads();
    find_bin(hist,part,1024,Krem,tid,&sB,&sLob);
    T=(pre<<10)|(unsigned)sB; Krem-=sLob;
    __syncthreads();
    for (int i=tid;i<total;i+=256){ unsigned k=buf[i]; if (k<T) CONTRIB(k); }
  } else {
    // fallback (P ~ 1e-10): exact fp32 full recompute select
    if (tid==0) s_cnt=0;
    for (int i=tid;i<dp;i+=256) qrow[i]=Qm[(size_t)q*dp+i];
    __syncthreads();
    float qq=qn[q];
    auto KEY=[&](int t)->unsigned{
      const float* br=&Tm[(size_t)t*dp];
      float dot=0.f;
      for (int k2=0;k2<dp;k2++) dot+=qrow[k2]*br[k2];
      float d2=fmaxf(qq-2.f*dot+tn[t],0.f);
      return (__float_as_uint(d2)&0xFFFFFFF8u)|(unsigned)labels[t];
    };
    for (int i=tid;i<2048;i+=256) hist[i]=0;
    __syncthreads();
    for (int t=tid;t<NT;t+=256) atomicAdd(&hist[KEY(t)>>21],1);
    __syncthreads();
    find_bin(hist,part,2048,Krem,tid,&sB,&sLob);
    int c=hist[sB]; Krem-=sLob;
    unsigned prefix=(unsigned)sB; int shift=21;
    if (c > CAP){
      __syncthreads();
      for (int i=tid;i<2048;i+=256) hist[i]=0;
      __syncthreads();
      for (int t=tid;t<NT;t+=256){ unsigned k=KEY(t); if ((k>>21)==prefix) atomicAdd(&hist[(k>>10)&0x7FFu],1); }
      __syncthreads();
      find_bin(hist,part,2048,Krem,tid,&sB,&sLob);
      c=hist[sB]; Krem-=sLob; prefix=(prefix<<11)|(unsigned)sB; shift=10;
    }
    if (c > CAP){
      __syncthreads();
      for (int i=tid;i<1024;i+=256) hist[i]=0;
      __syncthreads();
      for (int t=tid;t<NT;t+=256){ unsigned k=KEY(t); if ((k>>10)==prefix) atomicAdd(&hist[k&0x3FFu],1); }
      __syncthreads();
      find_bin(hist,part,1024,Krem,tid,&sB,&sLob);
      c=hist[sB]; Krem-=sLob; prefix=(prefix<<10)|(unsigned)sB; shift=0;
    }
    if (c <= CAP){
      for (int t=tid;t<NT;t+=256){
        unsigned k=KEY(t); unsigned pp=k>>shift;
        if (pp==prefix){ int j=atomicAdd(&s_cnt,1); if (j<CAP) buf[j]=k; }
        else if (pp<prefix){ int j=atomicAdd(&s_low,1); if (j<96) lowbuf[j]=k; }
      }
      __syncthreads();
      int sh=shift;
      while (sh>0){
        int nsh=(sh==21)?10:0;
        int nb=1<<(sh-nsh);
        __syncthreads();
        for (int i=tid;i<nb;i+=256) hist[i]=0;
        __syncthreads();
        int cc=s_cnt;
        for (int i=tid;i<cc;i+=256) atomicAdd(&hist[(buf[i]>>nsh)&(unsigned)(nb-1)],1);
        __syncthreads();
        find_bin(hist,part,nb,Krem,tid,&sB,&sLob);
        Krem-=sLob; prefix=(prefix<<(sh-nsh))|(unsigned)sB; sh=nsh;
      }
      T=prefix;
      __syncthreads();
      int lowc=s_low, cc=s_cnt;
      for (int i=tid;i<lowc;i+=256){ unsigned k=lowbuf[i]; CONTRIB(k); }
      for (int i=tid;i<cc;i+=256){ unsigned k=buf[i]; if (k<T) CONTRIB(k); }
    } else {
      T=prefix;
      for (int t=tid;t<NT;t+=256){ unsigned k=KEY(t); if (k<T) CONTRIB(k); }
    }
  }
  __syncthreads();
  if (tid==0){
    float d2=__uint_as_float(T&0xFFFFFFF8u);
    float w=(d2>0.f)?(1.0f/sqrtf(d2)):0.f;
    s_w[8] += (float)Krem*w;
    s_w[T&7u] += (float)Krem*w;
  }
  __syncthreads();
  if (tid<8){
    float contrib = s_w[8]-s_w[tid];
    size_t o=(size_t)q*NL+tid;
    tot[o] = first ? contrib : tot[o]+contrib;
  }
#undef CONTRIB
}

// ---------------- empirical p-values ------------------------------------------
__global__ void pvalue_k(const float* __restrict__ tot, const float* __restrict__ cali,
                         float* __restrict__ out){
  __shared__ float t8[NL];
  __shared__ int part[4][NL];
  int tid=threadIdx.x, q=blockIdx.x;
  if (tid<NL) t8[tid]=tot[(size_t)q*NL+tid];
  __syncthreads();
  float th[NL];
  #pragma unroll
  for (int c=0;c<NL;c++) th[c]=t8[c];
  int cnt[NL];
  #pragma unroll
  for (int c=0;c<NL;c++) cnt[c]=0;
  for (int i=tid;i<NCALI;i+=256){
    float v=cali[i];
    #pragma unroll
    for (int c=0;c<NL;c++) cnt[c] += (v>=th[c]) ? 1 : 0;
  }
  #pragma unroll
  for (int c=0;c<NL;c++){
    #pragma unroll
    for (int off=32;off>0;off>>=1) cnt[c]+=__shfl_down(cnt[c],off,64);
  }
  if ((tid&63)==0){
    #pragma unroll
    for (int c=0;c<NL;c++) part[tid>>6][c]=cnt[c];
  }
  __syncthreads();
  if (tid<NL){
    int s=part[0][tid]+part[1][tid]+part[2][tid]+part[3][tid];
    out[(size_t)q*NL+tid] = (float)s / 10000.f;
  }
}

extern "C" void kernel_launch(void* const* d_in, const int* in_sizes, int n_in,
                              void* d_out, int out_size, void* d_ws, size_t ws_size,
                              hipStream_t stream) {
  const float* x   = (const float*)d_in[0];
  const float* txr = (const float*)d_in[1];
  const int*   lbl = (const int*)  d_in[2];
  const float* cal = (const float*)d_in[3];
  const float* W1  = (const float*)d_in[4];
  const float* b1  = (const float*)d_in[5];
  const float* W2  = (const float*)d_in[6];
  const float* b2  = (const float*)d_in[7];
  const float* W3  = (const float*)d_in[8];
  const float* b3  = (const float*)d_in[9];
  const float* W4  = (const float*)d_in[10];
  const float* b4  = (const float*)d_in[11];
  float* out = (float*)d_out;
  float* ws  = (float*)d_ws;

  size_t off=0;
  float* xq0=ws+off; off+=(size_t)NB*96;
  float* xq1=ws+off; off+=(size_t)NB*128;
  float* xq2=ws+off; off+=(size_t)NB*128;
  float* xq3=ws+off; off+=(size_t)NB*128;
  float* xq4=ws+off; off+=(size_t)NB*32;
  float* tbA=ws+off; off+=(size_t)NT*128;
  float* tbB=ws+off; off+=(size_t)NT*128;
  float* tb4=ws+off; off+=(size_t)NT*32;
  float* qnb=ws+off; off+=(size_t)5*NB;
  float* tnb=ws+off; off+=(size_t)NT;
  float* Tsub=ws+off; off+=(size_t)NSUB*128;
  float* tnsub=ws+off; off+=(size_t)NSUB;
  float* tot=ws+off; off+=(size_t)NB*NL;
  unsigned* sT=(unsigned*)(ws+off); off+=NB;
  unsigned short* qsplit=(unsigned short*)(ws+off); off+=(size_t)5*2*NB*64;
  unsigned short* bankH=(unsigned short*)(ws+off); off+=(size_t)NT_PAD*64;
  unsigned short* bankL=(unsigned short*)(ws+off); off+=(size_t)NT_PAD*64;
  off=(off+3)&~(size_t)3;
  unsigned* slab=(unsigned*)(ws+off);   // NB*NTB*SLOTS = 25.6 MB
  unsigned* skeys=(unsigned*)(ws+off);  // NB*NSUB     =  8.4 MB (aliased)
  { size_t slab_sz=(size_t)NB*NTB*SLOTS, skey_sz=(size_t)NB*NSUB;
    off += (slab_sz > skey_sz ? slab_sz : skey_sz); }

  unsigned short* qH[5]; unsigned short* qL[5];
  for (int l=0;l<5;l++){
    qH[l]=qsplit + (size_t)l*2*NB*128;
    qL[l]=qH[l] + (size_t)NB*128;
  }

  // query features; layer-0 at stride 96. mlp_gemm fuses bf16-split + norms.
  pad_copy_k<<<(NB*96+255)/256,256,0,stream>>>(x, xq0, NB, 83, 96);
  pad_copy_k<<<((size_t)NT*96+255)/256,256,0,stream>>>(txr, tbA, NT, 83, 96);
  conv_norm_k<<<(NB+3)/4,256,0,stream>>>(xq0, qH[0], qL[0], qnb+0*NB, NB, 96);
  mlp_gemm_k<<<(NB+127)/128,256,0,stream>>>(xq0,96,3,W1,83,b1,xq1,qH[1],qL[1],qnb+1*NB,NB);
  mlp_gemm_k<<<(NB+127)/128,256,0,stream>>>(xq1,128,4,W2,128,b2,xq2,qH[2],qL[2],qnb+2*NB,NB);
  mlp_gemm_k<<<(NB+127)/128,256,0,stream>>>(xq2,128,4,W3,128,b3,xq3,qH[3],qL[3],qnb+3*NB,NB);
  mlp8_k<<<(NB+31)/32,256,0,stream>>>(xq3,W4,b4,xq4,NB);
  softmax_k<<<(NB+255)/256,256,0,stream>>>(xq4,NB);
  conv_norm_k<<<(NB+3)/4,256,0,stream>>>(xq4, qH[4], qL[4], qnb+4*NB, NB, 32);

  auto knn_layer = [&](const float* Qm, unsigned short* qh, unsigned short* ql,
                       const float* Bank, float* qnl, int dp, int first){
    sub_gather_k<<<(NSUB*dp+NSUB+255)/256,256,0,stream>>>(Bank,tnb,Tsub,tnsub,dp);
    dist_key_k<<<dim3(NB/QT,NSUB/TT),256,0,stream>>>(Qm,Tsub,qnl,tnsub,lbl,skeys,dp,NSUB);
    sel64_k<<<NB,256,0,stream>>>(skeys,sT);
    dist_mfma_k<<<8*8*49,256,0,stream>>>(qh,ql,bankH,bankL,qnl,tnb,lbl,sT,slab,dp);
    final_k<<<NB,256,0,stream>>>(slab,Qm,Bank,qnl,tnb,lbl,tot,first,dp);
  };

  // layer 0
  conv_norm_k<<<(NT+3)/4,256,0,stream>>>(tbA, bankH, bankL, tnb, NT, 96);
  knn_layer(xq0, qH[0], qL[0], tbA, qnb+0*NB, 96, 1);
  // layer 1 (mlp_gemm writes fp32 + bank hi/lo + tnb)
  mlp_gemm_k<<<(NT+127)/128,256,0,stream>>>(tbA,96,3,W1,83,b1,tbB,bankH,bankL,tnb,NT);
  knn_layer(xq1, qH[1], qL[1], tbB, qnb+1*NB, 128, 0);
  // layer 2
  mlp_gemm_k<<<(NT+127)/128,256,0,stream>>>(tbB,128,4,W2,128,b2,tbA,bankH,bankL,tnb,NT);
  knn_layer(xq2, qH[2], qL[2], tbA, qnb+2*NB, 128, 0);
  // layer 3
  mlp_gemm_k<<<(NT+127)/128,256,0,stream>>>(tbA,128,4,W3,128,b3,tbB,bankH,bankL,tnb,NT);
  knn_layer(xq3, qH[3], qL[3], tbB, qnb+3*NB, 128, 0);
  // layer 4
  mlp8_k<<<(NT+31)/32,256,0,stream>>>(tbB,W4,b4,tb4,NT);
  softmax_k<<<(NT+255)/256,256,0,stream>>>(tb4,NT);
  conv_norm_k<<<(NT+3)/4,256,0,stream>>>(tb4, bankH, bankL, tnb, NT, 32);
  knn_layer(xq4, qH[4], qL[4], tb4, qnb+4*NB, 32, 0);

  pvalue_k<<<NB,256,0,stream>>>(tot,cal,out);
}

// Round 12
// 1223.027 us; speedup vs baseline: 1.2497x; 1.0788x over previous
//
#include <hip/hip_runtime.h>
#include <math.h>

#define KNN 75
#define NL 8
#define NB 1024
#define NT 50000
#define NT_PAD 50048  // NTB*TT rows allocated for bf16 banks (pad rows masked)
#define NCALI 10000
#define KC 32
#define QT 64
#define TT 128
#define NTB 391       // ceil(NT/TT)
#define SLOTS 16      // per (q, t-block) slab: [count, up to 15 hit keys] = 64B
#define CAP 6144      // candidate buffer per query
#define NSUB 2048     // sampled train points for threshold
#define SSTRIDE 24
#define SOFF 11       // 11 + 24*2047 = 49139 < 50000
#define RSEL 32       // sample rank -> expected |{k < T}| ~ 780, lambda/slab ~ 2

typedef __attribute__((ext_vector_type(8))) short bf16x8;
typedef __attribute__((ext_vector_type(4))) float f32x4;

__device__ __forceinline__ int swz(int c){ return c + ((c>>5)<<2); }

__device__ __forceinline__ unsigned short f2bf_rn(float x){
  unsigned u = __float_as_uint(x);
  unsigned r = (u + 0x7FFFu + ((u>>16)&1u)) >> 16;
  return (unsigned short)r;
}
__device__ __forceinline__ float bf2f(unsigned short h){
  return __uint_as_float(((unsigned)h)<<16);
}
__device__ __forceinline__ bf16x8 ld8(const unsigned short* p){
  return *(const bf16x8*)p;
}
// async global->LDS, 16B per lane; LDS dest = wave-uniform base + lane*16
__device__ __forceinline__ void gl_lds16(const unsigned short* g, unsigned short* l){
  __builtin_amdgcn_global_load_lds(
      (const __attribute__((address_space(1))) void*)g,
      (__attribute__((address_space(3))) void*)l, 16, 0, 0);
}

// ---------------- pad copy (zero-fill pad cols every call: ws is poisoned) ----
__global__ void pad_copy_k(const float* __restrict__ in, float* __restrict__ out,
                           int M, int Din, int Dout){
  int idx = blockIdx.x*256 + threadIdx.x;
  if (idx >= M*Dout) return;
  int r = idx / Dout, c = idx - r*Dout;
  out[idx] = (c < Din) ? in[r*Din + c] : 0.f;
}

// ---------------- MLP GEMM: Out[M][128] = relu(A[M][lda] @ W[kreal][128] + b) --
__global__ __launch_bounds__(256) void mlp_gemm_k(
    const float* __restrict__ A, int lda, int kchunks,
    const float* __restrict__ W, int kreal,
    const float* __restrict__ bias,
    float* __restrict__ Out, int M)
{
  __shared__ float As[KC][132];
  __shared__ float Bs[KC][148];
  int tid = threadIdx.x;
  int r0 = (tid>>4)*8, c0 = (tid&15)*8;
  int rowBase = blockIdx.x*128;
  float acc[8][8];
  #pragma unroll
  for (int i=0;i<8;i++)
    #pragma unroll
    for (int j=0;j<8;j++) acc[i][j]=0.f;

  for (int kc=0;kc<kchunks;kc++){
    { int rr = tid>>3, k4=(tid&7)*4;
      #pragma unroll
      for (int i=0;i<4;i++){
        int row = rr + i*32, gr = rowBase + row;
        float4 v = make_float4(0.f,0.f,0.f,0.f);
        if (gr < M) v = *(const float4*)&A[(size_t)gr*lda + kc*KC + k4];
        As[k4+0][row]=v.x; As[k4+1][row]=v.y; As[k4+2][row]=v.z; As[k4+3][row]=v.w;
      }
    }
    { int kk=tid>>5, c4=(tid&31)*4;
      #pragma unroll
      for (int i=0;i<4;i++){
        int k = kk + i*8, gk = kc*KC + k;
        float4 v = make_float4(0.f,0.f,0.f,0.f);
        if (gk < kreal) v = *(const float4*)&W[(size_t)gk*128 + c4];
        *(float4*)&Bs[k][swz(c4)] = v;
      }
    }
    __syncthreads();
    #pragma unroll 4
    for (int k=0;k<KC;k++){
      float4 a0 = *(const float4*)&As[k][r0];
      float4 a1 = *(const float4*)&As[k][r0+4];
      float4 b0 = *(const float4*)&Bs[k][swz(c0)];
      float4 b1 = *(const float4*)&Bs[k][swz(c0+4)];
      float av[8] = {a0.x,a0.y,a0.z,a0.w,a1.x,a1.y,a1.z,a1.w};
      float bv[8] = {b0.x,b0.y,b0.z,b0.w,b1.x,b1.y,b1.z,b1.w};
      #pragma unroll
      for (int i=0;i<8;i++)
        #pragma unroll
        for (int j=0;j<8;j++) acc[i][j] += av[i]*bv[j];
    }
    __syncthreads();
  }
  float bb[8];
  #pragma unroll
  for (int j=0;j<8;j++) bb[j]=bias[c0+j];
  #pragma unroll
  for (int i=0;i<8;i++){
    int gr = rowBase + r0 + i;
    if (gr < M){
      float o[8];
      #pragma unroll
      for (int j=0;j<8;j++){ float v=acc[i][j]+bb[j]; o[j]=v>0.f?v:0.f; }
      *(float4*)&Out[(size_t)gr*128 + c0]   = make_float4(o[0],o[1],o[2],o[3]);
      *(float4*)&Out[(size_t)gr*128 + c0+4] = make_float4(o[4],o[5],o[6],o[7]);
    }
  }
}

// ---------------- last layer: logits[M][8] into stride-32 rows ----------------
__global__ void mlp8_k(const float* __restrict__ A, const float* __restrict__ W4,
                       const float* __restrict__ b4, float* __restrict__ Out, int M){
  __shared__ float Ws[128*8];
  int tid = threadIdx.x;
  for (int i=tid;i<1024;i+=256) Ws[i]=W4[i];
  __syncthreads();
  int r = blockIdx.x*32 + (tid>>3), c = tid&7;
  if (r >= M) return;
  const float* a = &A[(size_t)r*128];
  float acc = b4[c];
  #pragma unroll 16
  for (int k=0;k<128;k++) acc += a[k]*Ws[k*8+c];
  Out[(size_t)r*32 + c] = acc;
}

// ---------------- softmax over 8 logits, zero cols 8..31 ----------------------
__global__ void softmax_k(float* __restrict__ X, int M){
  int r = blockIdx.x*256 + threadIdx.x;
  if (r >= M) return;
  float* p = &X[(size_t)r*32];
  float v[8], m=-1e30f;
  #pragma unroll
  for (int j=0;j<8;j++){ v[j]=p[j]; m = v[j]>m ? v[j] : m; }
  float s=0.f;
  #pragma unroll
  for (int j=0;j<8;j++){ v[j]=__expf(v[j]-m); s+=v[j]; }
  float inv=1.f/s;
  #pragma unroll
  for (int j=0;j<8;j++) p[j]=v[j]*inv;
  #pragma unroll
  for (int j=8;j<32;j++) p[j]=0.f;
}

// ---------------- fp32 -> (hi,lo) bf16 split + row squared-norms --------------
__global__ void conv_norm_k(const float* __restrict__ X,
                            unsigned short* __restrict__ H,
                            unsigned short* __restrict__ L,
                            float* __restrict__ nrm, int M, int dp){
  int w = threadIdx.x>>6, lane = threadIdx.x&63;
  int row = blockIdx.x*4 + w;
  if (row >= M) return;
  const float* src = &X[(size_t)row*dp];
  unsigned short* dh = &H[(size_t)row*dp];
  unsigned short* dl = &L[(size_t)row*dp];
  float s=0.f;
  for (int c=lane;c<dp;c+=64){
    float v = src[c];
    s += v*v;
    unsigned short h = f2bf_rn(v);
    float rem = v - bf2f(h);
    dh[c] = h;
    dl[c] = f2bf_rn(rem);
  }
  #pragma unroll
  for (int off=32;off>0;off>>=1) s += __shfl_down(s, off, 64);
  if (lane==0) nrm[row]=s;
}

// ---------------- gather sampled subset bank + its norms ----------------------
__global__ void sub_gather_k(const float* __restrict__ Bank, const float* __restrict__ tnb,
                             float* __restrict__ Tsub, float* __restrict__ tnsub, int dp){
  int idx = blockIdx.x*256 + threadIdx.x;
  int total = NSUB*dp;
  if (idx < total){
    int s = idx/dp, c = idx - s*dp;
    Tsub[idx] = Bank[(size_t)(s*SSTRIDE+SOFF)*dp + c];
  } else if (idx < total + NSUB){
    int s = idx - total;
    tnsub[s] = tnb[s*SSTRIDE+SOFF];
  }
}

// ---------------- subset distance GEMM (fp32) -> packed keys ------------------
__global__ __launch_bounds__(256) void dist_key_k(
    const float* __restrict__ Qm, const float* __restrict__ Tm,
    const float* __restrict__ qn, const float* __restrict__ tn,
    const int* __restrict__ labels, unsigned* __restrict__ keys, int dp, int nt)
{
  __shared__ float qs[KC][68];
  __shared__ float ts[KC][148];
  int tid = threadIdx.x;
  int qbase = blockIdx.x*QT;
  int n0 = blockIdx.y*TT;
  int kchunks = dp >> 5;
  int r0 = (tid>>4)*4, c0=(tid&15)*8;
  float acc[4][8];
  #pragma unroll
  for (int i=0;i<4;i++)
    #pragma unroll
    for (int j=0;j<8;j++) acc[i][j]=0.f;

  for (int kc=0;kc<kchunks;kc++){
    { int qq0=tid>>3, k4=(tid&7)*4;
      #pragma unroll
      for (int i=0;i<2;i++){
        int qq=qq0+i*32;
        float4 v = *(const float4*)&Qm[(size_t)(qbase+qq)*dp + kc*KC + k4];
        qs[k4+0][qq]=v.x; qs[k4+1][qq]=v.y; qs[k4+2][qq]=v.z; qs[k4+3][qq]=v.w;
      }
    }
    { int tt0=tid>>3, k4=(tid&7)*4;
      #pragma unroll
      for (int i=0;i<4;i++){
        int ttI=tt0+i*32, g=n0+ttI;
        float4 v = make_float4(0.f,0.f,0.f,0.f);
        if (g < nt) v = *(const float4*)&Tm[(size_t)g*dp + kc*KC + k4];
        int o=swz(ttI);
        ts[k4+0][o]=v.x; ts[k4+1][o]=v.y; ts[k4+2][o]=v.z; ts[k4+3][o]=v.w;
      }
    }
    __syncthreads();
    #pragma unroll 8
    for (int k=0;k<KC;k++){
      float4 a  = *(const float4*)&qs[k][r0];
      float4 b0 = *(const float4*)&ts[k][swz(c0)];
      float4 b1 = *(const float4*)&ts[k][swz(c0+4)];
      float av[4]={a.x,a.y,a.z,a.w};
      float bv[8]={b0.x,b0.y,b0.z,b0.w,b1.x,b1.y,b1.z,b1.w};
      #pragma unroll
      for (int i=0;i<4;i++)
        #pragma unroll
        for (int j=0;j<8;j++) acc[i][j] += av[i]*bv[j];
    }
    __syncthreads();
  }
  int tl = nt - n0; if (tl > TT) tl = TT;
  if (c0 < tl){
    float qnr[4];
    #pragma unroll
    for (int i=0;i<4;i++) qnr[i]=qn[qbase+r0+i];
    float tnv[8]; unsigned labv[8];
    #pragma unroll
    for (int j=0;j<8;j++){ int g=n0+c0+j; tnv[j]=tn[g]; labv[j]=(unsigned)labels[g]; }
    #pragma unroll
    for (int i=0;i<4;i++){
      unsigned kk[8];
      #pragma unroll
      for (int j=0;j<8;j++){
        float d2 = fmaxf(qnr[i] - 2.f*acc[i][j] + tnv[j], 0.f);
        kk[j] = (__float_as_uint(d2)&0xFFFFFFF8u) | labv[j];
      }
      unsigned* dst = &keys[(size_t)(qbase+r0+i)*nt + n0+c0];
      *(uint4*)dst     = make_uint4(kk[0],kk[1],kk[2],kk[3]);
      *(uint4*)(dst+4) = make_uint4(kk[4],kk[5],kk[6],kk[7]);
    }
  }
}

// ---------------- scan helper: find bin containing rank Krem ------------------
__device__ __forceinline__ void find_bin(int* hist, int* part, int nb, int Krem,
                                         int tid, int* s_B, int* s_lob){
  int ch = nb>>8;
  int s=0;
  for (int b=tid*ch;b<tid*ch+ch;b++) s+=hist[b];
  part[tid]=s;
  __syncthreads();
  if (tid==0){
    int cum=0, B=nb-1, lob=0;
    for (int t=0;t<256;t++){
      if (cum+part[t] >= Krem){
        lob=cum;
        for (int b=t*ch;b<t*ch+ch;b++){
          if (lob+hist[b]>=Krem){ B=b; break; }
          lob+=hist[b];
        }
        break;
      }
      cum+=part[t];
    }
    *s_B=B; *s_lob=lob;
  }
  __syncthreads();
}

// ---------------- per-query threshold: exact RSEL-th smallest sample key ------
__global__ __launch_bounds__(256) void sel64_k(const unsigned* __restrict__ skeys,
                                               unsigned* __restrict__ Tthr){
  __shared__ unsigned buf[NSUB];
  __shared__ int hist[2048];
  __shared__ int part[256];
  __shared__ int sB, sLob;
  int tid=threadIdx.x, q=blockIdx.x;
  for (int i=tid;i<NSUB;i+=256) buf[i]=skeys[(size_t)q*NSUB+i];
  int Krem=RSEL;
  for (int i=tid;i<2048;i+=256) hist[i]=0;
  __syncthreads();
  for (int i=tid;i<NSUB;i+=256) atomicAdd(&hist[buf[i]>>21],1);
  __syncthreads();
  find_bin(hist,part,2048,Krem,tid,&sB,&sLob);
  unsigned pre=(unsigned)sB; Krem-=sLob;
  for (int i=tid;i<2048;i+=256) hist[i]=0;
  __syncthreads();
  for (int i=tid;i<NSUB;i+=256){ unsigned k=buf[i]; if ((k>>21)==pre) atomicAdd(&hist[(k>>10)&0x7FFu],1); }
  __syncthreads();
  find_bin(hist,part,2048,Krem,tid,&sB,&sLob);
  pre=(pre<<11)|(unsigned)sB; Krem-=sLob;
  for (int i=tid;i<1024;i+=256) hist[i]=0;
  __syncthreads();
  for (int i=tid;i<NSUB;i+=256){ unsigned k=buf[i]; if ((k>>10)==pre) atomicAdd(&hist[k&0x3FFu],1); }
  __syncthreads();
  find_bin(hist,part,1024,Krem,tid,&sB,&sLob);
  if (tid==0) Tthr[q]=(pre<<10)|(unsigned)sB;
}

// ---------------- MFMA split-bf16 distance GEMM, double-buffered staging ------
// 1D grid 8*8*49, XCD-swizzled (b&7 = stripe). Block = 128q x 128t.
// Staging for chunk k+1 issues right after the barrier and lands during chunk
// k's MFMA section -> barrier drain is cheap (pipelined). Two A register sets
// (manual 2x unroll) so the compiler's vmcnt wait on A doesn't serialize issue.
#define MFMA_SEC(CUR, A0H, A0L, A1H, A1L)                                        \
  _Pragma("unroll")                                                              \
  for (int tj=0;tj<8;tj++){                                                      \
    int rowB = tj*16 + col;                                                      \
    int sw = (((quad + (rowB>>1)) & 3) << 3);                                    \
    bf16x8 bh = *(const bf16x8*)&BH[CUR][rowB*32 + sw];                          \
    bf16x8 bl = *(const bf16x8*)&BL[CUR][rowB*32 + sw];                          \
    acc[0][tj] = __builtin_amdgcn_mfma_f32_16x16x32_bf16(A0H, bh, acc[0][tj], 0,0,0); \
    acc[0][tj] = __builtin_amdgcn_mfma_f32_16x16x32_bf16(A0H, bl, acc[0][tj], 0,0,0); \
    acc[0][tj] = __builtin_amdgcn_mfma_f32_16x16x32_bf16(A0L, bh, acc[0][tj], 0,0,0); \
    acc[1][tj] = __builtin_amdgcn_mfma_f32_16x16x32_bf16(A1H, bh, acc[1][tj], 0,0,0); \
    acc[1][tj] = __builtin_amdgcn_mfma_f32_16x16x32_bf16(A1H, bl, acc[1][tj], 0,0,0); \
    acc[1][tj] = __builtin_amdgcn_mfma_f32_16x16x32_bf16(A1L, bh, acc[1][tj], 0,0,0); \
  }

__global__ __launch_bounds__(256) void dist_mfma_k(
    const unsigned short* __restrict__ QH, const unsigned short* __restrict__ QL,
    const unsigned short* __restrict__ TH, const unsigned short* __restrict__ TL,
    const float* __restrict__ qn, const float* __restrict__ tn,
    const int* __restrict__ labels, const unsigned* __restrict__ Tthr,
    unsigned* __restrict__ slab, int dp)
{
  __shared__ unsigned short BH[2][128*32];   // 16 KB
  __shared__ unsigned short BL[2][128*32];   // 16 KB
  __shared__ unsigned hitbuf[128][SLOTS];    // 8 KB
  __shared__ int hcnt[128];
  int b = blockIdx.x;
  int xcd = b & 7, s = b >> 3;
  int qb = s & 7, tslot = s >> 3;
  int t_blk = xcd + 8*tslot;
  if (t_blk >= NTB) return;
  int tid = threadIdx.x, w = tid>>6, lane = tid&63;
  int quad = lane>>4, col = lane&15;
  int qbase = qb*128;
  int n0 = t_blk*TT;
  int kchunks = dp >> 5;

  size_t aoff = (size_t)(qbase + w*32 + col)*dp + quad*8;
  const unsigned short* pAH = QH + aoff;
  const unsigned short* pAL = QL + aoff;
  size_t qi_step = (size_t)16*dp;

  int i0 = tid,      row0 = i0>>2, sg0 = ((i0&3) - (row0>>1)) & 3;
  int i1 = tid+256,  row1 = i1>>2, sg1 = ((i1&3) - (row1>>1)) & 3;
  size_t g0 = (size_t)(n0+row0)*dp + (size_t)sg0*8;
  size_t g1 = (size_t)(n0+row1)*dp + (size_t)sg1*8;

  f32x4 acc[2][8];
  #pragma unroll
  for (int qi=0;qi<2;qi++)
    #pragma unroll
    for (int tj=0;tj<8;tj++){ f32x4 z={0.f,0.f,0.f,0.f}; acc[qi][tj]=z; }

  // prologue: stage chunk 0 into buf0, load A(0) into set X
  gl_lds16(TH + g0, &BH[0][i0*8]);
  gl_lds16(TH + g1, &BH[0][i1*8]);
  gl_lds16(TL + g0, &BL[0][i0*8]);
  gl_lds16(TL + g1, &BL[0][i1*8]);
  bf16x8 x0h = ld8(pAH), x0l = ld8(pAL);
  bf16x8 x1h = ld8(pAH + qi_step), x1l = ld8(pAL + qi_step);
  bf16x8 y0h = x0h, y0l = x0l, y1h = x1h, y1l = x1l;

  for (int kc=0; kc<kchunks; kc+=2){
    // even chunk: compute on buf0/setX, prefetch kc+1 -> buf1/setY
    __syncthreads();   // drains staging(kc)+A(kc); readers of buf1 (iter kc-1) done
    if (kc+1 < kchunks){
      size_t ko=(size_t)(kc+1)*32;
      gl_lds16(TH + g0 + ko, &BH[1][i0*8]);
      gl_lds16(TH + g1 + ko, &BH[1][i1*8]);
      gl_lds16(TL + g0 + ko, &BL[1][i0*8]);
      gl_lds16(TL + g1 + ko, &BL[1][i1*8]);
      y0h = ld8(pAH + ko);           y0l = ld8(pAL + ko);
      y1h = ld8(pAH + qi_step + ko); y1l = ld8(pAL + qi_step + ko);
    }
    MFMA_SEC(0, x0h, x0l, x1h, x1l);
    if (kc+1 < kchunks){
      // odd chunk: compute on buf1/setY, prefetch kc+2 -> buf0/setX
      __syncthreads();
      if (kc+2 < kchunks){
        size_t ko=(size_t)(kc+2)*32;
        gl_lds16(TH + g0 + ko, &BH[0][i0*8]);
        gl_lds16(TH + g1 + ko, &BH[0][i1*8]);
        gl_lds16(TL + g0 + ko, &BL[0][i0*8]);
        gl_lds16(TL + g1 + ko, &BL[0][i1*8]);
        x0h = ld8(pAH + ko);           x0l = ld8(pAL + ko);
        x1h = ld8(pAH + qi_step + ko); x1l = ld8(pAL + qi_step + ko);
      }
      MFMA_SEC(1, y0h, y0l, y1h, y1l);
    }
  }

  // epilogue: d2 from norms + acc, threshold compare, LDS slab compaction
  if (tid<128) hcnt[tid]=0;
  __syncthreads();
  float qnr[2][4]; unsigned Tq[2][4];
  #pragma unroll
  for (int qi=0;qi<2;qi++)
    #pragma unroll
    for (int r=0;r<4;r++){
      int q = qbase + w*32 + qi*16 + quad*4 + r;
      qnr[qi][r] = qn[q];
      Tq[qi][r]  = Tthr[q];
    }
  #pragma unroll
  for (int tj=0;tj<8;tj++){
    int t = n0 + tj*16 + col;
    if (t < NT){
      float tnv = tn[t];
      unsigned lab = (unsigned)labels[t];
      #pragma unroll
      for (int qi=0;qi<2;qi++)
        #pragma unroll
        for (int r=0;r<4;r++){
          float d2 = fmaxf(qnr[qi][r] - 2.f*acc[qi][tj][r] + tnv, 0.f);
          unsigned key = (__float_as_uint(d2)&0xFFFFFFF8u) | lab;
          if (key < Tq[qi][r]){
            int ql = w*32 + qi*16 + quad*4 + r;
            int idx = atomicAdd(&hcnt[ql], 1);
            if (idx < SLOTS-1) hitbuf[ql][1+idx] = key;
          }
        }
    }
  }
  __syncthreads();
  if (tid<128) hitbuf[tid][0]=(unsigned)hcnt[tid];
  __syncthreads();
  #pragma unroll
  for (int rep=0; rep<2; rep++){
    int idx = rep*256 + tid;
    int q = idx>>2, sub = (idx&3)*4;
    uint4 v = *(uint4*)&hitbuf[q][sub];
    *(uint4*)&slab[((size_t)(qbase+q)*NTB + t_blk)*SLOTS + sub] = v;
  }
}

// ---------------- gather slabs, exact radix select + class sums ---------------
__global__ __launch_bounds__(256) void final_k(
    const unsigned* __restrict__ slab,
    const float* __restrict__ Qm, const float* __restrict__ Tm,
    const float* __restrict__ qn, const float* __restrict__ tn,
    const int* __restrict__ labels,
    float* __restrict__ tot, int first, int dp)
{
  __shared__ int hist[2048];
  __shared__ int part[256];
  __shared__ unsigned buf[CAP];
  __shared__ unsigned lowbuf[96];
  __shared__ float qrow[128];
  __shared__ int sB,sLob,s_cnt,s_low,s_bad;
  __shared__ float s_w[9];
  int tid=threadIdx.x, q=blockIdx.x;
  if (tid==0){ for (int j=0;j<9;j++) s_w[j]=0.f; s_cnt=0; s_low=0; s_bad=0; }
  __syncthreads();

  const unsigned* sq = slab + (size_t)q*NTB*SLOTS;
  for (int sidx=tid; sidx<NTB; sidx+=256){
    const unsigned* s = sq + (size_t)sidx*SLOTS;
    uint4 a = *(const uint4*)s;
    unsigned cnt = a.x;
    if (cnt > SLOTS-1){ s_bad=1; continue; }
    if (!cnt) continue;
    int base = atomicAdd(&s_cnt, (int)cnt);
    if (base + (int)cnt <= CAP){
      buf[base] = a.y;
      if (cnt>=2) buf[base+1] = a.z;
      if (cnt>=3) buf[base+2] = a.w;
      for (unsigned w=4; w<=cnt; w++) buf[base+w-1] = s[w];
    }
  }
  __syncthreads();
  int total = s_cnt;
  int bad = s_bad;

#define CONTRIB(kk) do{ float d2_=__uint_as_float((kk)&0xFFFFFFF8u); \
    if (d2_>0.f){ float w_=1.0f/sqrtf(d2_); \
      atomicAdd(&s_w[8],w_); atomicAdd(&s_w[(kk)&7u],w_); } }while(0)

  unsigned T; int Krem=KNN;
  if (!bad && total>=KNN && total<=CAP){
    for (int i=tid;i<2048;i+=256) hist[i]=0;
    __syncthreads();
    for (int i=tid;i<total;i+=256) atomicAdd(&hist[buf[i]>>21],1);
    __syncthreads();
    find_bin(hist,part,2048,Krem,tid,&sB,&sLob);
    unsigned pre=(unsigned)sB; Krem-=sLob;
    for (int i=tid;i<2048;i+=256) hist[i]=0;
    __syncthreads();
    for (int i=tid;i<total;i+=256){ unsigned k=buf[i]; if ((k>>21)==pre) atomicAdd(&hist[(k>>10)&0x7FFu],1); }
    __syncthreads();
    find_bin(hist,part,2048,Krem,tid,&sB,&sLob);
    pre=(pre<<11)|(unsigned)sB; Krem-=sLob;
    for (int i=tid;i<1024;i+=256) hist[i]=0;
    __syncthreads();
    for (int i=tid;i<total;i+=256){ unsigned k=buf[i]; if ((k>>10)==pre) atomicAdd(&hist[k&0x3FFu],1); }
    __syncthreads();
    find_bin(hist,part,1024,Krem,tid,&sB,&sLob);
    T=(pre<<10)|(unsigned)sB; Krem-=sLob;
    __syncthreads();
    for (int i=tid;i<total;i+=256){ unsigned k=buf[i]; if (k<T) CONTRIB(k); }
  } else {
    // fallback (P ~ 1e-10): exact fp32 full recompute select
    if (tid==0) s_cnt=0;
    for (int i=tid;i<dp;i+=256) qrow[i]=Qm[(size_t)q*dp+i];
    __syncthreads();
    float qq=qn[q];
    auto KEY=[&](int t)->unsigned{
      const float* br=&Tm[(size_t)t*dp];
      float dot=0.f;
      for (int k2=0;k2<dp;k2++) dot+=qrow[k2]*br[k2];
      float d2=fmaxf(qq-2.f*dot+tn[t],0.f);
      return (__float_as_uint(d2)&0xFFFFFFF8u)|(unsigned)labels[t];
    };
    for (int i=tid;i<2048;i+=256) hist[i]=0;
    __syncthreads();
    for (int t=tid;t<NT;t+=256) atomicAdd(&hist[KEY(t)>>21],1);
    __syncthreads();
    find_bin(hist,part,2048,Krem,tid,&sB,&sLob);
    int c=hist[sB]; Krem-=sLob;
    unsigned prefix=(unsigned)sB; int shift=21;
    if (c > CAP){
      __syncthreads();
      for (int i=tid;i<2048;i+=256) hist[i]=0;
      __syncthreads();
      for (int t=tid;t<NT;t+=256){ unsigned k=KEY(t); if ((k>>21)==prefix) atomicAdd(&hist[(k>>10)&0x7FFu],1); }
      __syncthreads();
      find_bin(hist,part,2048,Krem,tid,&sB,&sLob);
      c=hist[sB]; Krem-=sLob; prefix=(prefix<<11)|(unsigned)sB; shift=10;
    }
    if (c > CAP){
      __syncthreads();
      for (int i=tid;i<1024;i+=256) hist[i]=0;
      __syncthreads();
      for (int t=tid;t<NT;t+=256){ unsigned k=KEY(t); if ((k>>10)==prefix) atomicAdd(&hist[k&0x3FFu],1); }
      __syncthreads();
      find_bin(hist,part,1024,Krem,tid,&sB,&sLob);
      c=hist[sB]; Krem-=sLob; prefix=(prefix<<10)|(unsigned)sB; shift=0;
    }
    if (c <= CAP){
      for (int t=tid;t<NT;t+=256){
        unsigned k=KEY(t); unsigned pp=k>>shift;
        if (pp==prefix){ int j=atomicAdd(&s_cnt,1); if (j<CAP) buf[j]=k; }
        else if (pp<prefix){ int j=atomicAdd(&s_low,1); if (j<96) lowbuf[j]=k; }
      }
      __syncthreads();
      int sh=shift;
      while (sh>0){
        int nsh=(sh==21)?10:0;
        int nb=1<<(sh-nsh);
        __syncthreads();
        for (int i=tid;i<nb;i+=256) hist[i]=0;
        __syncthreads();
        int cc=s_cnt;
        for (int i=tid;i<cc;i+=256) atomicAdd(&hist[(buf[i]>>nsh)&(unsigned)(nb-1)],1);
        __syncthreads();
        find_bin(hist,part,nb,Krem,tid,&sB,&sLob);
        Krem-=sLob; prefix=(prefix<<(sh-nsh))|(unsigned)sB; sh=nsh;
      }
      T=prefix;
      __syncthreads();
      int lowc=s_low, cc=s_cnt;
      for (int i=tid;i<lowc;i+=256){ unsigned k=lowbuf[i]; CONTRIB(k); }
      for (int i=tid;i<cc;i+=256){ unsigned k=buf[i]; if (k<T) CONTRIB(k); }
    } else {
      T=prefix;
      for (int t=tid;t<NT;t+=256){ unsigned k=KEY(t); if (k<T) CONTRIB(k); }
    }
  }
  __syncthreads();
  if (tid==0){
    float d2=__uint_as_float(T&0xFFFFFFF8u);
    float w=(d2>0.f)?(1.0f/sqrtf(d2)):0.f;
    s_w[8] += (float)Krem*w;
    s_w[T&7u] += (float)Krem*w;
  }
  __syncthreads();
  if (tid<8){
    float contrib = s_w[8]-s_w[tid];
    size_t o=(size_t)q*NL+tid;
    tot[o] = first ? contrib : tot[o]+contrib;
  }
#undef CONTRIB
}

// ---------------- empirical p-values ------------------------------------------
__global__ void pvalue_k(const float* __restrict__ tot, const float* __restrict__ cali,
                         float* __restrict__ out){
  __shared__ float t8[NL];
  __shared__ int part[4][NL];
  int tid=threadIdx.x, q=blockIdx.x;
  if (tid<NL) t8[tid]=tot[(size_t)q*NL+tid];
  __syncthreads();
  float th[NL];
  #pragma unroll
  for (int c=0;c<NL;c++) th[c]=t8[c];
  int cnt[NL];
  #pragma unroll
  for (int c=0;c<NL;c++) cnt[c]=0;
  for (int i=tid;i<NCALI;i+=256){
    float v=cali[i];
    #pragma unroll
    for (int c=0;c<NL;c++) cnt[c] += (v>=th[c]) ? 1 : 0;
  }
  #pragma unroll
  for (int c=0;c<NL;c++){
    #pragma unroll
    for (int off=32;off>0;off>>=1) cnt[c]+=__shfl_down(cnt[c],off,64);
  }
  if ((tid&63)==0){
    #pragma unroll
    for (int c=0;c<NL;c++) part[tid>>6][c]=cnt[c];
  }
  __syncthreads();
  if (tid<NL){
    int s=part[0][tid]+part[1][tid]+part[2][tid]+part[3][tid];
    out[(size_t)q*NL+tid] = (float)s / 10000.f;
  }
}

extern "C" void kernel_launch(void* const* d_in, const int* in_sizes, int n_in,
                              void* d_out, int out_size, void* d_ws, size_t ws_size,
                              hipStream_t stream) {
  const float* x   = (const float*)d_in[0];
  const float* txr = (const float*)d_in[1];
  const int*   lbl = (const int*)  d_in[2];
  const float* cal = (const float*)d_in[3];
  const float* W1  = (const float*)d_in[4];
  const float* b1  = (const float*)d_in[5];
  const float* W2  = (const float*)d_in[6];
  const float* b2  = (const float*)d_in[7];
  const float* W3  = (const float*)d_in[8];
  const float* b3  = (const float*)d_in[9];
  const float* W4  = (const float*)d_in[10];
  const float* b4  = (const float*)d_in[11];
  float* out = (float*)d_out;
  float* ws  = (float*)d_ws;

  size_t off=0;
  float* xq0=ws+off; off+=(size_t)NB*96;
  float* xq1=ws+off; off+=(size_t)NB*128;
  float* xq2=ws+off; off+=(size_t)NB*128;
  float* xq3=ws+off; off+=(size_t)NB*128;
  float* xq4=ws+off; off+=(size_t)NB*32;
  float* tbA=ws+off; off+=(size_t)NT*128;
  float* tbB=ws+off; off+=(size_t)NT*128;
  float* tb4=ws+off; off+=(size_t)NT*32;
  float* qnb=ws+off; off+=(size_t)5*NB;
  float* tnb=ws+off; off+=(size_t)NT;
  float* Tsub=ws+off; off+=(size_t)NSUB*128;
  float* tnsub=ws+off; off+=(size_t)NSUB;
  float* tot=ws+off; off+=(size_t)NB*NL;
  unsigned* sT=(unsigned*)(ws+off); off+=NB;
  unsigned short* qH=(unsigned short*)(ws+off); off+=(size_t)NB*64;
  unsigned short* qL=(unsigned short*)(ws+off); off+=(size_t)NB*64;
  unsigned short* bankH=(unsigned short*)(ws+off); off+=(size_t)NT_PAD*64;
  unsigned short* bankL=(unsigned short*)(ws+off); off+=(size_t)NT_PAD*64;
  off=(off+3)&~(size_t)3;
  unsigned* slab=(unsigned*)(ws+off);   // NB*NTB*SLOTS = 25.6 MB
  unsigned* skeys=(unsigned*)(ws+off);  // NB*NSUB     =  8.4 MB (aliased)
  { size_t slab_sz=(size_t)NB*NTB*SLOTS, skey_sz=(size_t)NB*NSUB;
    off += (slab_sz > skey_sz ? slab_sz : skey_sz); }

  // query features; layer-0 features at stride 96
  pad_copy_k<<<(NB*96+255)/256,256,0,stream>>>(x, xq0, NB, 83, 96);
  pad_copy_k<<<((size_t)NT*96+255)/256,256,0,stream>>>(txr, tbA, NT, 83, 96);
  mlp_gemm_k<<<(NB+127)/128,256,0,stream>>>(xq0,96,3,W1,83,b1,xq1,NB);
  mlp_gemm_k<<<(NB+127)/128,256,0,stream>>>(xq1,128,4,W2,128,b2,xq2,NB);
  mlp_gemm_k<<<(NB+127)/128,256,0,stream>>>(xq2,128,4,W3,128,b3,xq3,NB);
  mlp8_k<<<(NB+31)/32,256,0,stream>>>(xq3,W4,b4,xq4,NB);
  softmax_k<<<(NB+255)/256,256,0,stream>>>(xq4,NB);

  auto knn_layer = [&](const float* Qm, const float* Bank, float* qnl,
                       int dp, int first){
    conv_norm_k<<<(NT+3)/4,256,0,stream>>>(Bank, bankH, bankL, tnb, NT, dp);
    conv_norm_k<<<(NB+3)/4,256,0,stream>>>(Qm, qH, qL, qnl, NB, dp);
    sub_gather_k<<<(NSUB*dp+NSUB+255)/256,256,0,stream>>>(Bank,tnb,Tsub,tnsub,dp);
    dist_key_k<<<dim3(NB/QT,NSUB/TT),256,0,stream>>>(Qm,Tsub,qnl,tnsub,lbl,skeys,dp,NSUB);
    sel64_k<<<NB,256,0,stream>>>(skeys,sT);
    dist_mfma_k<<<8*8*49,256,0,stream>>>(qH,qL,bankH,bankL,qnl,tnb,lbl,sT,slab,dp);
    final_k<<<NB,256,0,stream>>>(slab,Qm,Bank,qnl,tnb,lbl,tot,first,dp);
  };

  knn_layer(xq0, tbA, qnb+0*NB, 96, 1);
  mlp_gemm_k<<<(NT+127)/128,256,0,stream>>>(tbA,96,3,W1,83,b1,tbB,NT);
  knn_layer(xq1, tbB, qnb+1*NB, 128, 0);
  mlp_gemm_k<<<(NT+127)/128,256,0,stream>>>(tbB,128,4,W2,128,b2,tbA,NT);
  knn_layer(xq2, tbA, qnb+2*NB, 128, 0);
  mlp_gemm_k<<<(NT+127)/128,256,0,stream>>>(tbA,128,4,W3,128,b3,tbB,NT);
  knn_layer(xq3, tbB, qnb+3*NB, 128, 0);
  mlp8_k<<<(NT+31)/32,256,0,stream>>>(tbB,W4,b4,tb4,NT);
  softmax_k<<<(NT+255)/256,256,0,stream>>>(tb4,NT);
  knn_layer(xq4, tb4, qnb+4*NB, 32, 0);

  pvalue_k<<<NB,256,0,stream>>>(tot,cal,out);
}